// Round 4
// baseline (155.210 us; speedup 1.0000x reference)
//
#include <hip/hip_runtime.h>
#include <math.h>

#define B_ 8
#define CIN_ 512
#define K_ 64
#define V_ 256
#define T_ 1024
#define KS_ 23
#define EPS_ 1e-5f
#define NTC_ 8   // lambda t-chunks (each lambda block accumulates 2 chunks in regs)

typedef __attribute__((ext_vector_type(8))) short bf16x8;
typedef __attribute__((ext_vector_type(4))) float f32x4;

__device__ __forceinline__ unsigned short f2bf(float f) {
    union { float f; unsigned u; } x; x.f = f;
    unsigned r = x.u + 0x7fffu + ((x.u >> 16) & 1u);   // RNE
    return (unsigned short)(r >> 16);
}
__device__ __forceinline__ float bf2f(unsigned short h) {
    union { unsigned u; float f; } x; x.u = ((unsigned)h) << 16;
    return x.f;
}

// async global->LDS, 16B per lane; LDS dest is wave-uniform base + lane*16
__device__ __forceinline__ void gload16(const unsigned short* g, unsigned short* l) {
    __builtin_amdgcn_global_load_lds(
        (const __attribute__((address_space(1))) unsigned int*)(const void*)g,
        (__attribute__((address_space(3))) unsigned int*)(void*)l, 16, 0, 0);
}

// ---------------------------------------------------------------------------
// prep: merged cvtT (blocks 0..2047) + prew (blocks 2048..2239).
// Also zeroes stat[640] + hterm[2048] (contiguous) for downstream atomics.
// ---------------------------------------------------------------------------
__global__ __launch_bounds__(256) void prep_kernel(
    const float* __restrict__ x, const float* __restrict__ ctx,
    const float* __restrict__ Wq, const float* __restrict__ Wk,
    const float* __restrict__ Wv,
    unsigned short* __restrict__ xT, unsigned short* __restrict__ cT,
    unsigned short* __restrict__ Wb, float* __restrict__ stat)
{
    __shared__ unsigned short sh[64][72];
    const int tid = threadIdx.x;
    const int id = blockIdx.x;
    if (id < 2048) {
        const int t0 = (id & 15) * 64, c0 = ((id >> 4) & 7) * 64;
        const int z = id >> 7, b = z & 7, which = z >> 3;
        const float* src = which ? ctx : x;
        unsigned short* dst = which ? cT : xT;
        const int cl = tid >> 2, qq = tid & 3;
        const float* row = src + ((size_t)b * CIN_ + c0 + cl) * T_ + t0 + qq * 16;
        #pragma unroll
        for (int u = 0; u < 4; u++) {
            float4 f = *(const float4*)(row + 4 * u);
            sh[qq * 16 + 4 * u + 0][cl] = f2bf(f.x);
            sh[qq * 16 + 4 * u + 1][cl] = f2bf(f.y);
            sh[qq * 16 + 4 * u + 2][cl] = f2bf(f.z);
            sh[qq * 16 + 4 * u + 3][cl] = f2bf(f.w);
        }
        __syncthreads();
        const int tl = tid >> 2;
        unsigned short* orow = dst + ((size_t)b * T_ + t0 + tl) * CIN_ + c0 + qq * 16;
        *(bf16x8*)(orow)     = *(bf16x8*)&sh[tl][qq * 16];
        *(bf16x8*)(orow + 8) = *(bf16x8*)&sh[tl][qq * 16 + 8];
    } else {
        const int wid = id - 2048;
        if (wid == 0) {
            // zero stat (640 f) + hterm (2048 f) = 672 float4
            #pragma unroll
            for (int i = 0; i < 3; i++) {
                int idx = tid + i * 256;
                if (idx < 672) ((float4*)stat)[idx] = make_float4(0.f, 0.f, 0.f, 0.f);
            }
        }
        const int i4 = wid * 256 + tid;
        const int n1 = K_ * CIN_ / 4, n2 = 2 * K_ * CIN_ / 4;
        const float* src; int off;
        if (i4 < n1)      { src = Wq; off = i4; }
        else if (i4 < n2) { src = Wk; off = i4 - n1; }
        else              { src = Wv; off = i4 - n2; }
        float4 f = ((const float4*)src)[off];
        ushort4 h;
        h.x = f2bf(f.x); h.y = f2bf(f.y); h.z = f2bf(f.z); h.w = f2bf(f.w);
        *(ushort4*)(Wb + (size_t)i4 * 4) = h;
    }
}

// ---------------------------------------------------------------------------
// proj_mfma7: bf16 MFMA projection, t-tile 64 (768 blocks = 3/CU balanced),
// double-buffered global_load_lds staging with counted vmcnt(4).
// XOR swizzle on BOTH the per-lane global source chunk and the MFMA read.
// kml now has 16 t-segments (one per 64-t block).
// ---------------------------------------------------------------------------
__global__ __launch_bounds__(256) void proj_mfma7(
    const unsigned short* __restrict__ xT, const unsigned short* __restrict__ cT,
    const unsigned short* __restrict__ Wb,
    const float* __restrict__ bq, const float* __restrict__ bk,
    const float* __restrict__ bv,
    float* __restrict__ k_buf, float* __restrict__ v_raw,
    unsigned short* __restrict__ qT, float* __restrict__ stat,
    float* __restrict__ kml)
{
    // per buffer: Wt[64][64] (4096 ush) + Xt[64][64] (4096 ush) = 16 KB
    __shared__ __align__(16) unsigned short SMb[2][8192];

    const int tid = threadIdx.x;
    const int b = blockIdx.z, t0 = blockIdx.x * 64, yb = blockIdx.y;

    const unsigned short* in; const unsigned short* W; const float* bias;
    float* outp = nullptr; int ch0 = 0; float* ssum = nullptr; float* ssq = nullptr;
    if (yb == 0)      { in = xT; W = Wb;             bias = bq;
                        ssum = stat; ssq = stat + 64; ch0 = 0; }
    else if (yb == 1) { in = cT; W = Wb + K_ * CIN_; bias = bk;
                        outp = k_buf + (size_t)b * K_ * T_; }
    else { int m0 = (yb - 2) * 64; in = cT;
           W = Wb + 2 * K_ * CIN_ + (size_t)m0 * CIN_; bias = bv + m0;
           outp = v_raw + ((size_t)b * V_ + m0) * T_;
           ssum = stat + 128; ssq = stat + 384; ch0 = m0; }

    const int lane = tid & 63, w = tid >> 6;
    const int col = lane & 15, quad = lane >> 4;

    // staging pointers: chunk g -> row r=g>>3, phys chunk c=g&7 holds
    // global chunk (c ^ (r&7)).  LDS dest base is wave-uniform.
    const int gW0 = (0 * 4 + w) * 64 + lane, rW0 = gW0 >> 3;
    const int gW1 = (1 * 4 + w) * 64 + lane, rW1 = gW1 >> 3;
    const unsigned short* sW0 = W + (size_t)rW0 * CIN_ + (((gW0 & 7) ^ (rW0 & 7)) * 8);
    const unsigned short* sW1 = W + (size_t)rW1 * CIN_ + (((gW1 & 7) ^ (rW1 & 7)) * 8);

    const int gX0 = (0 * 4 + w) * 64 + lane, rX0 = gX0 >> 3;
    const int gX1 = (1 * 4 + w) * 64 + lane, rX1 = gX1 >> 3;
    const size_t xbase = (size_t)b * T_ + t0;
    const unsigned short* sX0 = in + (xbase + rX0) * CIN_ + (((gX0 & 7) ^ (rX0 & 7)) * 8);
    const unsigned short* sX1 = in + (xbase + rX1) * CIN_ + (((gX1 & 7) ^ (rX1 & 7)) * 8);

#define STAGE(P, C0) do { \
    unsigned short* Wt_ = SMb[P]; \
    unsigned short* Xt_ = SMb[P] + 4096; \
    gload16(sW0 + (C0), Wt_ + w * 512); \
    gload16(sW1 + (C0), Wt_ + 2048 + w * 512); \
    gload16(sX0 + (C0), Xt_ + w * 512); \
    gload16(sX1 + (C0), Xt_ + 2048 + w * 512); \
} while (0)

    f32x4 acc[4];
    #pragma unroll
    for (int j = 0; j < 4; j++) acc[j] = (f32x4){0.f, 0.f, 0.f, 0.f};

    STAGE(0, 0);
    for (int s = 0; s < 8; s++) {          // CIN_/64 = 8 K-steps
        const int cur = s & 1;
        if (s < 7) {
            STAGE(cur ^ 1, (s + 1) * 64);
            asm volatile("s_waitcnt vmcnt(4)" ::: "memory");   // current tile done
        } else {
            asm volatile("s_waitcnt vmcnt(0)" ::: "memory");
        }
        __builtin_amdgcn_s_barrier();
        __builtin_amdgcn_sched_barrier(0);
        {
            const unsigned short* Wt = SMb[cur];
            const unsigned short* Xt = SMb[cur] + 4096;
            #pragma unroll
            for (int ks = 0; ks < 2; ks++) {
                const int kc = ((ks * 4 + quad) ^ (col & 7)) * 8;
                bf16x8 af = *(bf16x8*)&Wt[(w * 16 + col) * 64 + kc];
                #pragma unroll
                for (int j = 0; j < 4; j++) {
                    bf16x8 bfr = *(bf16x8*)&Xt[(j * 16 + col) * 64 + kc];
                    acc[j] = __builtin_amdgcn_mfma_f32_16x16x32_bf16(af, bfr, acc[j], 0, 0, 0);
                }
            }
        }
        __builtin_amdgcn_sched_barrier(0);
        __builtin_amdgcn_s_barrier();
    }
#undef STAGE

    float bias_v[4], s_[4], sq[4], mr[4], lr[4];
    #pragma unroll
    for (int r = 0; r < 4; r++) {
        bias_v[r] = bias[w * 16 + quad * 4 + r];
        s_[r] = 0.f; sq[r] = 0.f; mr[r] = -1e30f; lr[r] = 0.f;
    }
    unsigned short* SE = SMb[0];   // epilogue transpose buffer [64][72]
    #pragma unroll
    for (int j = 0; j < 4; j++) {
        float o[4];
        #pragma unroll
        for (int r = 0; r < 4; r++) {
            o[r] = acc[j][r] + bias_v[r];
            s_[r] += o[r]; sq[r] += o[r] * o[r];
        }
        if (yb == 0) {
            ushort4 h;
            h.x = f2bf(o[0]); h.y = f2bf(o[1]); h.z = f2bf(o[2]); h.w = f2bf(o[3]);
            *(ushort4*)&SE[(j * 16 + col) * 72 + w * 16 + quad * 4] = h;
        } else {
            #pragma unroll
            for (int r = 0; r < 4; r++)
                outp[(size_t)(w * 16 + quad * 4 + r) * T_ + t0 + j * 16 + col] = o[r];
            if (yb == 1) {
                #pragma unroll
                for (int r = 0; r < 4; r++) {
                    float mn = fmaxf(mr[r], o[r]);
                    lr[r] = lr[r] * __expf(mr[r] - mn) + __expf(o[r] - mn);
                    mr[r] = mn;
                }
            }
        }
    }
    if (yb == 0) {
        // coalesced qT write: 64 rows x 128B, 32B per thread
        __syncthreads();
        const int tr = tid >> 2, part = tid & 3;
        unsigned short* dq = qT + ((size_t)b * T_ + t0 + tr) * K_ + part * 16;
        *(bf16x8*)(dq)     = *(bf16x8*)&SE[tr * 72 + part * 16];
        *(bf16x8*)(dq + 8) = *(bf16x8*)&SE[tr * 72 + part * 16 + 8];
    }
    if (yb == 1) {
        // cross-lane online-softmax combine over the 16 cols (same rows)
        #pragma unroll
        for (int r = 0; r < 4; r++) {
            float m = mr[r], l = lr[r];
            #pragma unroll
            for (int off = 1; off < 16; off <<= 1) {
                float mo = __shfl_xor(m, off, 64);
                float lo = __shfl_xor(l, off, 64);
                float mn = fmaxf(m, mo);
                l = l * __expf(m - mn) + lo * __expf(mo - mn);
                m = mn;
            }
            if (col == 0) {
                int row = w * 16 + quad * 4 + r;
                float* p = kml + (((size_t)b * K_ + row) * 16 + (t0 >> 6)) * 2;
                p[0] = m; p[1] = l;
            }
        }
    } else {
        #pragma unroll
        for (int r = 0; r < 4; r++) {
            float sv = s_[r], qv = sq[r];
            #pragma unroll
            for (int off = 1; off < 16; off <<= 1) {
                sv += __shfl_xor(sv, off, 64);
                qv += __shfl_xor(qv, off, 64);
            }
            if (col == 0) {
                int ch = ch0 + w * 16 + quad * 4 + r;
                atomicAdd(&ssum[ch], sv);
                atomicAdd(&ssq[ch], qv);
            }
        }
    }
}

// ---------------------------------------------------------------------------
// lambda6: combine 16-segment kml partials -> (m, 1/l); each block processes
// TWO 64-t chunks, accumulating in registers -> clp (NTC_=8), no atomics.
// ---------------------------------------------------------------------------
__global__ __launch_bounds__(256) void lambda_kernel6(
    const float* __restrict__ k_buf, const float* __restrict__ v_raw,
    const float* __restrict__ kml, float* __restrict__ clp)
{
    __shared__ __align__(16) float nks[K_][68];
    __shared__ __align__(16) float vls[64][68];
    __shared__ float mrow[64], lrow[64];
    const int tid = threadIdx.x;
    const int b = blockIdx.z, v0 = blockIdx.y * 64, tc = blockIdx.x;

    if (tid < 64) {
        const float2* p = (const float2*)(kml + ((size_t)b * K_ + tid) * 32);
        float m = -1e30f, l = 0.f;
        #pragma unroll
        for (int sgi = 0; sgi < 16; sgi++) {
            float2 ml = p[sgi];
            float mn = fmaxf(m, ml.x);
            l = l * __expf(m - mn) + ml.y * __expf(ml.x - mn);
            m = mn;
        }
        mrow[tid] = m; lrow[tid] = 1.f / l;
    }
    __syncthreads();

    const int r = tid >> 2, q = tid & 3;
    const int tv = tid & 15, tk = tid >> 4;
    float4 acc[4];
    #pragma unroll
    for (int i = 0; i < 4; i++) acc[i] = make_float4(0.f, 0.f, 0.f, 0.f);

    for (int c2 = 0; c2 < 2; c2++) {
        const int t0 = (tc * 2 + c2) * 64;
        if (c2) __syncthreads();           // prior chunk's reads done
        {
            const float* nrow = k_buf + ((size_t)b * K_ + r) * T_ + t0;
            const float* vrow = v_raw + ((size_t)b * V_ + v0 + r) * T_ + t0;
            const float mr = mrow[r], li = lrow[r];
            #pragma unroll
            for (int i = 0; i < 4; i++) {
                int c4 = q + 4 * i;
                float4 g = *(const float4*)(nrow + 4 * c4);
                g.x = __expf(g.x - mr) * li; g.y = __expf(g.y - mr) * li;
                g.z = __expf(g.z - mr) * li; g.w = __expf(g.w - mr) * li;
                *(float4*)&nks[r][4 * c4] = g;
                float4 h = *(const float4*)(vrow + 4 * c4);
                vls[4 * c4 + 0][r] = h.x; vls[4 * c4 + 1][r] = h.y;
                vls[4 * c4 + 2][r] = h.z; vls[4 * c4 + 3][r] = h.w;
            }
        }
        __syncthreads();
        for (int tt = 0; tt < 16; tt++) {
            float4 w0 = *(float4*)&vls[4 * tt + 0][4 * tv];
            float4 w1 = *(float4*)&vls[4 * tt + 1][4 * tv];
            float4 w2 = *(float4*)&vls[4 * tt + 2][4 * tv];
            float4 w3 = *(float4*)&vls[4 * tt + 3][4 * tv];
            #pragma unroll
            for (int i = 0; i < 4; i++) {
                float4 n = *(float4*)&nks[4 * tk + i][4 * tt];
                acc[i] += w0 * n.x + w1 * n.y + w2 * n.z + w3 * n.w;
            }
        }
    }
    #pragma unroll
    for (int i = 0; i < 4; i++)
        *(float4*)&clp[(((size_t)b * NTC_ + tc) * K_ + 4 * tk + i) * V_ + v0 + 4 * tv] = acc[i];
}

// ---------------------------------------------------------------------------
// prep_cl3: sum clp partials; 4-way k-split over blockIdx.z;
// hterm accumulated via atomicAdd (zeroed in prep).
// ---------------------------------------------------------------------------
__global__ __launch_bounds__(256) void prep_cl_kernel3(
    const float* __restrict__ clp, const float* __restrict__ stat,
    const float* __restrict__ gq, const float* __restrict__ betaq,
    const float* __restrict__ gv, const float* __restrict__ betav,
    unsigned short* __restrict__ clb2, float* __restrict__ hterm)
{
    __shared__ float qsc[64], qsh[64], red[4][64];
    const int tid = threadIdx.x;
    const int b = blockIdx.y, v0 = blockIdx.x * 64, kz = blockIdx.z;
    const float inv_n = 1.f / (B_ * T_);
    if (tid < 64) {
        float mean = stat[tid] * inv_n;
        float var  = stat[64 + tid] * inv_n - mean * mean;
        float sc = gq[tid] * rsqrtf(var + EPS_);
        qsc[tid] = sc; qsh[tid] = betaq[tid] - mean * sc;
    }
    const int vl = tid & 63, kq = tid >> 6;
    const int c = v0 + vl;
    float vmean = stat[128 + c] * inv_n;
    float vvar  = stat[384 + c] * inv_n - vmean * vmean;
    float vsv = gv[c] * rsqrtf(vvar + EPS_);
    float vhv = betav[c] - vmean * vsv;
    __syncthreads();
    float h = 0.f;
    #pragma unroll
    for (int kk = 0; kk < 4; kk++) {
        int k = kz * 16 + kq * 4 + kk;
        float a = 0.f;
        #pragma unroll
        for (int tc = 0; tc < NTC_; tc++)
            a += clp[(((size_t)b * NTC_ + tc) * K_ + k) * V_ + c];
        float clbv = a * vsv + vhv;
        h += qsh[k] * clbv;
        clb2[((size_t)b * V_ + c) * K_ + k] = f2bf(clbv * qsc[k]);
    }
    red[kq][vl] = h;
    __syncthreads();
    if (tid < 64)
        atomicAdd(&hterm[(size_t)b * V_ + v0 + tid],
                  red[0][tid] + red[1][tid] + red[2][tid] + red[3][tid]);
}

// ---------------------------------------------------------------------------
// out5: fused qp + content-MFMA + conv epilogue. qpt padded 24->28 floats.
// ---------------------------------------------------------------------------
__global__ __launch_bounds__(256) void out_kernel5(
    const unsigned short* __restrict__ qT, const unsigned short* __restrict__ clb2,
    const float* __restrict__ hterm, const float* __restrict__ v_raw,
    const float* __restrict__ stat,
    const float* __restrict__ gq, const float* __restrict__ betaq,
    const float* __restrict__ gv, const float* __restrict__ betav,
    const float* __restrict__ pos_w, const float* __restrict__ pos_b,
    float* __restrict__ out)
{
    __shared__ unsigned short qTt[64][72];
    __shared__ unsigned short clv[64][72];
    __shared__ float vs2T[88][68];
    __shared__ float qpt[64][28];
    __shared__ float pws[64][24];
    __shared__ float qsc[64], qsh[64];
    __shared__ float consts[24];
    __shared__ float hvs[64];
    const int tid = threadIdx.x;
    const int b = blockIdx.z, v0 = blockIdx.y * 64, t0 = blockIdx.x * 64;
    const float inv_n = 1.f / (B_ * T_);

    if (tid < 64) {
        float mean = stat[tid] * inv_n;
        float var  = stat[64 + tid] * inv_n - mean * mean;
        float sc = gq[tid] * rsqrtf(var + EPS_);
        qsc[tid] = sc; qsh[tid] = betaq[tid] - mean * sc;
        hvs[tid] = hterm[(size_t)b * V_ + v0 + tid];
    }
    {
        const int rl = tid >> 2, part = tid & 3;
        const unsigned short* qs = qT + ((size_t)b * T_ + t0 + rl) * K_ + part * 16;
        *(bf16x8*)&qTt[rl][part * 16]     = *(const bf16x8*)(qs);
        *(bf16x8*)&qTt[rl][part * 16 + 8] = *(const bf16x8*)(qs + 8);
        const unsigned short* cs = clb2 + ((size_t)b * V_ + v0 + rl) * K_ + part * 16;
        *(bf16x8*)&clv[rl][part * 16]     = *(const bf16x8*)(cs);
        *(bf16x8*)&clv[rl][part * 16 + 8] = *(const bf16x8*)(cs + 8);
    }
    {
        const int vl = tid >> 2, qq = tid & 3;
        const int c = v0 + vl;
        float vmean = stat[128 + c] * inv_n;
        float vvar  = stat[384 + c] * inv_n - vmean * vmean;
        float vsv = gv[c] * rsqrtf(vvar + EPS_);
        float vhv = betav[c] - vmean * vsv;
        const float* vrow = v_raw + ((size_t)b * V_ + c) * T_;
        #pragma unroll
        for (int i = 0; i < 22; i++) {
            int cc = qq + 4 * i;
            if (cc < 86) {
                int t = t0 + cc - 11;
                vs2T[cc][vl] = (t >= 0 && t < T_) ? vrow[t] * vsv + vhv : 0.f;
            }
        }
    }
    __syncthreads();

    for (int idx = tid; idx < K_ * 24; idx += 256) {
        int k = idx / 24, s = idx % 24;
        pws[k][s] = qsc[k] * (s < KS_ ? pos_w[k * KS_ + s] : pos_b[k]);
    }
    if (tid < 24) {
        float cs = 0.f;
        for (int k = 0; k < K_; k++)
            cs += qsh[k] * (tid < KS_ ? pos_w[k * KS_ + tid] : pos_b[k]);
        consts[tid] = cs;
    }
    __syncthreads();

    {
        const int t = tid >> 2, sg = tid & 3, s0 = sg * 6;
        float a[6];
        #pragma unroll
        for (int u = 0; u < 6; u++) a[u] = consts[s0 + u];
        #pragma unroll
        for (int kb = 0; kb < 8; kb++) {
            bf16x8 qv = *(bf16x8*)&qTt[t][kb * 8];
            #pragma unroll
            for (int j = 0; j < 8; j++) {
                float q = bf2f((unsigned short)qv[j]);
                #pragma unroll
                for (int u = 0; u < 6; u++) a[u] += q * pws[kb * 8 + j][s0 + u];
            }
        }
        #pragma unroll
        for (int u = 0; u < 6; u++) qpt[t][s0 + u] = a[u];
    }
    __syncthreads();

    const int lane = tid & 63, w = tid >> 6;
    const int col = lane & 15, quad = lane >> 4;

    f32x4 acc[4];
    #pragma unroll
    for (int tf = 0; tf < 4; tf++) acc[tf] = (f32x4){0.f, 0.f, 0.f, 0.f};

    #pragma unroll
    for (int ks = 0; ks < 2; ks++) {
        const int kc = ks * 32 + quad * 8;
        bf16x8 af = *(bf16x8*)&clv[w * 16 + col][kc];
        #pragma unroll
        for (int tf = 0; tf < 4; tf++) {
            bf16x8 bq = *(bf16x8*)&qTt[tf * 16 + col][kc];
            acc[tf] = __builtin_amdgcn_mfma_f32_16x16x32_bf16(af, bq, acc[tf], 0, 0, 0);
        }
    }

    const int vb = w * 16 + quad * 4;
    float4 hv4 = *(float4*)&hvs[vb];
    #pragma unroll
    for (int tf = 0; tf < 4; tf++) {
        const int lt = tf * 16 + col;
        float qv[24];
        #pragma unroll
        for (int u = 0; u < 6; u++)
            *(float4*)&qv[4 * u] = *(float4*)&qpt[lt][4 * u];
        float4 a; a.x = acc[tf][0]; a.y = acc[tf][1]; a.z = acc[tf][2]; a.w = acc[tf][3];
        #pragma unroll
        for (int s = 0; s < KS_; s++) {
            float4 wv = *(float4*)&vs2T[lt + s][vb];
            a.x += qv[s] * wv.x; a.y += qv[s] * wv.y;
            a.z += qv[s] * wv.z; a.w += qv[s] * wv.w;
        }
        float base = qv[23];
        a.x += base + hv4.x; a.y += base + hv4.y;
        a.z += base + hv4.z; a.w += base + hv4.w;
        float* ap = (float*)&a;
        #pragma unroll
        for (int r = 0; r < 4; r++)
            out[((size_t)b * V_ + v0 + vb + r) * T_ + t0 + lt] = ap[r];
    }
}

extern "C" void kernel_launch(void* const* d_in, const int* in_sizes, int n_in,
                              void* d_out, int out_size, void* d_ws, size_t ws_size,
                              hipStream_t stream)
{
    const float* x     = (const float*)d_in[0];
    const float* ctx   = (const float*)d_in[1];
    const float* Wq    = (const float*)d_in[2];
    const float* bq    = (const float*)d_in[3];
    const float* Wk    = (const float*)d_in[4];
    const float* bk    = (const float*)d_in[5];
    const float* Wv    = (const float*)d_in[6];
    const float* bv    = (const float*)d_in[7];
    const float* gq    = (const float*)d_in[8];
    const float* betaq = (const float*)d_in[9];
    const float* gv    = (const float*)d_in[10];
    const float* betav = (const float*)d_in[11];
    const float* pos_w = (const float*)d_in[12];
    const float* pos_b = (const float*)d_in[13];
    float* out = (float*)d_out;

    float* ws    = (float*)d_ws;
    float* k_buf = ws;                                   // B*K*T      = 524288
    float* v_raw = k_buf + (size_t)B_ * K_ * T_;         // B*V*T      = 2097152
    float* clp   = v_raw + (size_t)B_ * V_ * T_;         // B*NTC*K*V  = 1048576
    float* stat  = clp + (size_t)B_ * NTC_ * K_ * V_;    // 640
    float* hterm = stat + 640;                           // B*V = 2048
    float* kml   = hterm + (size_t)B_ * V_;              // B*K*16*2 = 16384
    unsigned short* xT   = (unsigned short*)(kml + (size_t)B_ * K_ * 32);
    unsigned short* cT   = xT + (size_t)B_ * T_ * CIN_;
    unsigned short* Wb   = cT + (size_t)B_ * T_ * CIN_;
    unsigned short* qT   = Wb + (size_t)(2 * K_ + V_) * CIN_;
    unsigned short* clb2 = qT + (size_t)B_ * T_ * K_;

    prep_kernel<<<dim3(2048 + 192), 256, 0, stream>>>(
        x, ctx, Wq, Wk, Wv, xT, cT, Wb, stat);
    proj_mfma7<<<dim3(T_ / 64, 6, B_), 256, 0, stream>>>(
        xT, cT, Wb, bq, bk, bv, k_buf, v_raw, qT, stat, kml);
    lambda_kernel6<<<dim3(NTC_, V_ / 64, B_), 256, 0, stream>>>(k_buf, v_raw, kml, clp);
    prep_cl_kernel3<<<dim3(V_ / 64, B_, 4), 256, 0, stream>>>(
        clp, stat, gq, betaq, gv, betav, clb2, hterm);
    out_kernel5<<<dim3(T_ / 64, V_ / 64, B_), 256, 0, stream>>>(
        qT, clb2, hterm, v_raw, stat, gq, betaq, gv, betav, pos_w, pos_b, out);
}

// Round 5
// 153.548 us; speedup vs baseline: 1.0108x; 1.0108x over previous
//
#include <hip/hip_runtime.h>
#include <math.h>

#define B_ 8
#define CIN_ 512
#define K_ 64
#define V_ 256
#define T_ 1024
#define KS_ 23
#define EPS_ 1e-5f
#define NTC_ 8   // lambda t-chunks (each lambda block accumulates 2 chunks in regs)

typedef __attribute__((ext_vector_type(8))) short bf16x8;
typedef __attribute__((ext_vector_type(4))) float f32x4;

__device__ __forceinline__ unsigned short f2bf(float f) {
    union { float f; unsigned u; } x; x.f = f;
    unsigned r = x.u + 0x7fffu + ((x.u >> 16) & 1u);   // RNE
    return (unsigned short)(r >> 16);
}
__device__ __forceinline__ float bf2f(unsigned short h) {
    union { unsigned u; float f; } x; x.u = ((unsigned)h) << 16;
    return x.f;
}

// async global->LDS, 16B per lane; LDS dest is wave-uniform base + lane*16
__device__ __forceinline__ void gload16(const unsigned short* g, unsigned short* l) {
    __builtin_amdgcn_global_load_lds(
        (const __attribute__((address_space(1))) unsigned int*)(const void*)g,
        (__attribute__((address_space(3))) unsigned int*)(void*)l, 16, 0, 0);
}

// ---------------------------------------------------------------------------
// prep: merged cvtT (blocks 0..2047) + prew (blocks 2048..2239).
// Zeroes stat[640] for downstream atomics.
// ---------------------------------------------------------------------------
__global__ __launch_bounds__(256) void prep_kernel(
    const float* __restrict__ x, const float* __restrict__ ctx,
    const float* __restrict__ Wq, const float* __restrict__ Wk,
    const float* __restrict__ Wv,
    unsigned short* __restrict__ xT, unsigned short* __restrict__ cT,
    unsigned short* __restrict__ Wb, float* __restrict__ stat)
{
    __shared__ unsigned short sh[64][72];
    const int tid = threadIdx.x;
    const int id = blockIdx.x;
    if (id < 2048) {
        const int t0 = (id & 15) * 64, c0 = ((id >> 4) & 7) * 64;
        const int z = id >> 7, b = z & 7, which = z >> 3;
        const float* src = which ? ctx : x;
        unsigned short* dst = which ? cT : xT;
        const int cl = tid >> 2, qq = tid & 3;
        const float* row = src + ((size_t)b * CIN_ + c0 + cl) * T_ + t0 + qq * 16;
        #pragma unroll
        for (int u = 0; u < 4; u++) {
            float4 f = *(const float4*)(row + 4 * u);
            sh[qq * 16 + 4 * u + 0][cl] = f2bf(f.x);
            sh[qq * 16 + 4 * u + 1][cl] = f2bf(f.y);
            sh[qq * 16 + 4 * u + 2][cl] = f2bf(f.z);
            sh[qq * 16 + 4 * u + 3][cl] = f2bf(f.w);
        }
        __syncthreads();
        const int tl = tid >> 2;
        unsigned short* orow = dst + ((size_t)b * T_ + t0 + tl) * CIN_ + c0 + qq * 16;
        *(bf16x8*)(orow)     = *(bf16x8*)&sh[tl][qq * 16];
        *(bf16x8*)(orow + 8) = *(bf16x8*)&sh[tl][qq * 16 + 8];
    } else {
        const int wid = id - 2048;
        if (wid == 0 && tid < 160)
            ((float4*)stat)[tid] = make_float4(0.f, 0.f, 0.f, 0.f);
        const int i4 = wid * 256 + tid;
        const int n1 = K_ * CIN_ / 4, n2 = 2 * K_ * CIN_ / 4;
        const float* src; int off;
        if (i4 < n1)      { src = Wq; off = i4; }
        else if (i4 < n2) { src = Wk; off = i4 - n1; }
        else              { src = Wv; off = i4 - n2; }
        float4 f = ((const float4*)src)[off];
        ushort4 h;
        h.x = f2bf(f.x); h.y = f2bf(f.y); h.z = f2bf(f.z); h.w = f2bf(f.w);
        *(ushort4*)(Wb + (size_t)i4 * 4) = h;
    }
}

// ---------------------------------------------------------------------------
// proj_mfma6 (R3-proven): t-tile 128, double-buffered global_load_lds
// staging with counted vmcnt(6). XOR swizzle on BOTH the per-lane global
// source chunk and the MFMA read address.
// ---------------------------------------------------------------------------
__global__ __launch_bounds__(256) void proj_mfma6(
    const unsigned short* __restrict__ xT, const unsigned short* __restrict__ cT,
    const unsigned short* __restrict__ Wb,
    const float* __restrict__ bq, const float* __restrict__ bk,
    const float* __restrict__ bv,
    float* __restrict__ k_buf, float* __restrict__ v_raw,
    unsigned short* __restrict__ qT, float* __restrict__ stat,
    float* __restrict__ kml)
{
    // per buffer: Wt[64][64] (4096 ush) + Xt[128][64] (8192 ush) = 24 KB
    __shared__ __align__(16) unsigned short SMb[2][12288];

    const int tid = threadIdx.x;
    const int b = blockIdx.z, t0 = blockIdx.x * 128, yb = blockIdx.y;

    const unsigned short* in; const unsigned short* W; const float* bias;
    float* outp = nullptr; int ch0 = 0; float* ssum = nullptr; float* ssq = nullptr;
    if (yb == 0)      { in = xT; W = Wb;             bias = bq;
                        ssum = stat; ssq = stat + 64; ch0 = 0; }
    else if (yb == 1) { in = cT; W = Wb + K_ * CIN_; bias = bk;
                        outp = k_buf + (size_t)b * K_ * T_; }
    else { int m0 = (yb - 2) * 64; in = cT;
           W = Wb + 2 * K_ * CIN_ + (size_t)m0 * CIN_; bias = bv + m0;
           outp = v_raw + ((size_t)b * V_ + m0) * T_;
           ssum = stat + 128; ssq = stat + 384; ch0 = m0; }

    const int lane = tid & 63, w = tid >> 6;
    const int col = lane & 15, quad = lane >> 4;

    // staging pointers: chunk g -> row r=g>>3, phys chunk c=g&7 holds
    // global chunk (c ^ (r&7)).  LDS dest base is wave-uniform.
    const int gW0 = (0 * 4 + w) * 64 + lane, rW0 = gW0 >> 3;
    const int gW1 = (1 * 4 + w) * 64 + lane, rW1 = gW1 >> 3;
    const unsigned short* sW0 = W + (size_t)rW0 * CIN_ + (((gW0 & 7) ^ (rW0 & 7)) * 8);
    const unsigned short* sW1 = W + (size_t)rW1 * CIN_ + (((gW1 & 7) ^ (rW1 & 7)) * 8);

    const int gX0 = (0 * 4 + w) * 64 + lane, rX0 = gX0 >> 3;
    const int gX1 = (1 * 4 + w) * 64 + lane, rX1 = gX1 >> 3;
    const int gX2 = (2 * 4 + w) * 64 + lane, rX2 = gX2 >> 3;
    const int gX3 = (3 * 4 + w) * 64 + lane, rX3 = gX3 >> 3;
    const size_t xbase = (size_t)b * T_ + t0;
    const unsigned short* sX0 = in + (xbase + rX0) * CIN_ + (((gX0 & 7) ^ (rX0 & 7)) * 8);
    const unsigned short* sX1 = in + (xbase + rX1) * CIN_ + (((gX1 & 7) ^ (rX1 & 7)) * 8);
    const unsigned short* sX2 = in + (xbase + rX2) * CIN_ + (((gX2 & 7) ^ (rX2 & 7)) * 8);
    const unsigned short* sX3 = in + (xbase + rX3) * CIN_ + (((gX3 & 7) ^ (rX3 & 7)) * 8);

#define STAGE(P, C0) do { \
    unsigned short* Wt_ = SMb[P]; \
    unsigned short* Xt_ = SMb[P] + 4096; \
    gload16(sW0 + (C0), Wt_ + w * 512); \
    gload16(sW1 + (C0), Wt_ + 2048 + w * 512); \
    gload16(sX0 + (C0), Xt_ + w * 512); \
    gload16(sX1 + (C0), Xt_ + 2048 + w * 512); \
    gload16(sX2 + (C0), Xt_ + 4096 + w * 512); \
    gload16(sX3 + (C0), Xt_ + 6144 + w * 512); \
} while (0)

    f32x4 acc[8];
    #pragma unroll
    for (int j = 0; j < 8; j++) acc[j] = (f32x4){0.f, 0.f, 0.f, 0.f};

    STAGE(0, 0);
    for (int s = 0; s < 8; s++) {          // CIN_/64 = 8 K-steps
        const int cur = s & 1;
        if (s < 7) {
            STAGE(cur ^ 1, (s + 1) * 64);
            asm volatile("s_waitcnt vmcnt(6)" ::: "memory");   // current tile done
        } else {
            asm volatile("s_waitcnt vmcnt(0)" ::: "memory");
        }
        __builtin_amdgcn_s_barrier();
        __builtin_amdgcn_sched_barrier(0);
        {
            const unsigned short* Wt = SMb[cur];
            const unsigned short* Xt = SMb[cur] + 4096;
            #pragma unroll
            for (int ks = 0; ks < 2; ks++) {
                const int kc = ((ks * 4 + quad) ^ (col & 7)) * 8;
                bf16x8 af = *(bf16x8*)&Wt[(w * 16 + col) * 64 + kc];
                #pragma unroll
                for (int j = 0; j < 8; j++) {
                    bf16x8 bfr = *(bf16x8*)&Xt[(j * 16 + col) * 64 + kc];
                    acc[j] = __builtin_amdgcn_mfma_f32_16x16x32_bf16(af, bfr, acc[j], 0, 0, 0);
                }
            }
        }
        __builtin_amdgcn_sched_barrier(0);
        __builtin_amdgcn_s_barrier();
    }
#undef STAGE

    float bias_v[4], s_[4], sq[4], mr[4], lr[4];
    #pragma unroll
    for (int r = 0; r < 4; r++) {
        bias_v[r] = bias[w * 16 + quad * 4 + r];
        s_[r] = 0.f; sq[r] = 0.f; mr[r] = -1e30f; lr[r] = 0.f;
    }
    unsigned short* SE = SMb[0];   // epilogue transpose buffer [128][72]
    #pragma unroll
    for (int j = 0; j < 8; j++) {
        float o[4];
        #pragma unroll
        for (int r = 0; r < 4; r++) {
            o[r] = acc[j][r] + bias_v[r];
            s_[r] += o[r]; sq[r] += o[r] * o[r];
        }
        if (yb == 0) {
            ushort4 h;
            h.x = f2bf(o[0]); h.y = f2bf(o[1]); h.z = f2bf(o[2]); h.w = f2bf(o[3]);
            *(ushort4*)&SE[(j * 16 + col) * 72 + w * 16 + quad * 4] = h;
        } else {
            #pragma unroll
            for (int r = 0; r < 4; r++)
                outp[(size_t)(w * 16 + quad * 4 + r) * T_ + t0 + j * 16 + col] = o[r];
            if (yb == 1) {
                #pragma unroll
                for (int r = 0; r < 4; r++) {
                    float mn = fmaxf(mr[r], o[r]);
                    lr[r] = lr[r] * __expf(mr[r] - mn) + __expf(o[r] - mn);
                    mr[r] = mn;
                }
            }
        }
    }
    if (yb == 0) {
        // coalesced qT write: 128 rows x 128B, 64B per thread
        __syncthreads();
        const int tr = tid >> 1, h2 = tid & 1;
        unsigned short* dq = qT + ((size_t)b * T_ + t0 + tr) * K_ + h2 * 32;
        #pragma unroll
        for (int u = 0; u < 4; u++)
            *(bf16x8*)(dq + u * 8) = *(bf16x8*)&SE[tr * 72 + h2 * 32 + u * 8];
    }
    if (yb == 1) {
        // cross-lane online-softmax combine over the 16 cols (same rows)
        #pragma unroll
        for (int r = 0; r < 4; r++) {
            float m = mr[r], l = lr[r];
            #pragma unroll
            for (int off = 1; off < 16; off <<= 1) {
                float mo = __shfl_xor(m, off, 64);
                float lo = __shfl_xor(l, off, 64);
                float mn = fmaxf(m, mo);
                l = l * __expf(m - mn) + lo * __expf(mo - mn);
                m = mn;
            }
            if (col == 0) {
                int row = w * 16 + quad * 4 + r;
                float* p = kml + (((size_t)b * K_ + row) * 8 + (t0 >> 7)) * 2;
                p[0] = m; p[1] = l;
            }
        }
    } else {
        #pragma unroll
        for (int r = 0; r < 4; r++) {
            float sv = s_[r], qv = sq[r];
            #pragma unroll
            for (int off = 1; off < 16; off <<= 1) {
                sv += __shfl_xor(sv, off, 64);
                qv += __shfl_xor(qv, off, 64);
            }
            if (col == 0) {
                int ch = ch0 + w * 16 + quad * 4 + r;
                atomicAdd(&ssum[ch], sv);
                atomicAdd(&ssq[ch], qv);
            }
        }
    }
}

// ---------------------------------------------------------------------------
// lambda5: combine kml partials -> (m, 1/l); each block processes TWO 64-t
// chunks, accumulating in registers -> clp (NTC_=8), no atomics.
// ---------------------------------------------------------------------------
__global__ __launch_bounds__(256) void lambda_kernel5(
    const float* __restrict__ k_buf, const float* __restrict__ v_raw,
    const float* __restrict__ kml, float* __restrict__ clp)
{
    __shared__ __align__(16) float nks[K_][68];
    __shared__ __align__(16) float vls[64][68];
    __shared__ float mrow[64], lrow[64];
    const int tid = threadIdx.x;
    const int b = blockIdx.z, v0 = blockIdx.y * 64, tc = blockIdx.x;

    if (tid < 64) {
        const float2* p = (const float2*)(kml + ((size_t)b * K_ + tid) * 16);
        float m = -1e30f, l = 0.f;
        #pragma unroll
        for (int sgi = 0; sgi < 8; sgi++) {
            float2 ml = p[sgi];
            float mn = fmaxf(m, ml.x);
            l = l * __expf(m - mn) + ml.y * __expf(ml.x - mn);
            m = mn;
        }
        mrow[tid] = m; lrow[tid] = 1.f / l;
    }
    __syncthreads();

    const int r = tid >> 2, q = tid & 3;
    const int tv = tid & 15, tk = tid >> 4;
    float4 acc[4];
    #pragma unroll
    for (int i = 0; i < 4; i++) acc[i] = make_float4(0.f, 0.f, 0.f, 0.f);

    for (int c2 = 0; c2 < 2; c2++) {
        const int t0 = (tc * 2 + c2) * 64;
        if (c2) __syncthreads();           // prior chunk's reads done
        {
            const float* nrow = k_buf + ((size_t)b * K_ + r) * T_ + t0;
            const float* vrow = v_raw + ((size_t)b * V_ + v0 + r) * T_ + t0;
            const float mr = mrow[r], li = lrow[r];
            #pragma unroll
            for (int i = 0; i < 4; i++) {
                int c4 = q + 4 * i;
                float4 g = *(const float4*)(nrow + 4 * c4);
                g.x = __expf(g.x - mr) * li; g.y = __expf(g.y - mr) * li;
                g.z = __expf(g.z - mr) * li; g.w = __expf(g.w - mr) * li;
                *(float4*)&nks[r][4 * c4] = g;
                float4 h = *(const float4*)(vrow + 4 * c4);
                vls[4 * c4 + 0][r] = h.x; vls[4 * c4 + 1][r] = h.y;
                vls[4 * c4 + 2][r] = h.z; vls[4 * c4 + 3][r] = h.w;
            }
        }
        __syncthreads();
        for (int tt = 0; tt < 16; tt++) {
            float4 w0 = *(float4*)&vls[4 * tt + 0][4 * tv];
            float4 w1 = *(float4*)&vls[4 * tt + 1][4 * tv];
            float4 w2 = *(float4*)&vls[4 * tt + 2][4 * tv];
            float4 w3 = *(float4*)&vls[4 * tt + 3][4 * tv];
            #pragma unroll
            for (int i = 0; i < 4; i++) {
                float4 n = *(float4*)&nks[4 * tk + i][4 * tt];
                acc[i] += w0 * n.x + w1 * n.y + w2 * n.z + w3 * n.w;
            }
        }
    }
    #pragma unroll
    for (int i = 0; i < 4; i++)
        *(float4*)&clp[(((size_t)b * NTC_ + tc) * K_ + 4 * tk + i) * V_ + v0 + 4 * tv] = acc[i];
}

// ---------------------------------------------------------------------------
// out_kernel6: prep_cl FUSED IN.  Each block sums its own clp slice (8 tc
// partials for (b, v0)), applies BN inline, writes clv to LDS directly, and
// computes the hterm reduction in-register (shfl over k within wave + small
// LDS cross-wave combine).  clb2/hterm buffers and the prep_cl kernel gone.
// ---------------------------------------------------------------------------
__global__ __launch_bounds__(256) void out_kernel6(
    const unsigned short* __restrict__ qT, const float* __restrict__ clp,
    const float* __restrict__ v_raw, const float* __restrict__ stat,
    const float* __restrict__ gq, const float* __restrict__ betaq,
    const float* __restrict__ gv, const float* __restrict__ betav,
    const float* __restrict__ pos_w, const float* __restrict__ pos_b,
    float* __restrict__ out)
{
    __shared__ unsigned short qTt[64][72];
    __shared__ unsigned short clv[64][72];
    __shared__ float vs2T[88][68];
    __shared__ float qpt[64][28];
    __shared__ float pws[64][24];
    __shared__ float qsc[64], qsh[64], vsc[64], vsh[64];
    __shared__ float consts[24];
    __shared__ float hvs[64];
    __shared__ float hred[4][4][16];
    const int tid = threadIdx.x;
    const int b = blockIdx.z, v0 = blockIdx.y * 64, t0 = blockIdx.x * 64;
    const float inv_n = 1.f / (B_ * T_);

    // ---- stage A: BN params, qTt load, vs2T fill, clp partial sums (regs)
    if (tid < 64) {
        float mean = stat[tid] * inv_n;
        float var  = stat[64 + tid] * inv_n - mean * mean;
        float sc = gq[tid] * rsqrtf(var + EPS_);
        qsc[tid] = sc; qsh[tid] = betaq[tid] - mean * sc;
        int c = v0 + tid;
        float vmean = stat[128 + c] * inv_n;
        float vvar  = stat[384 + c] * inv_n - vmean * vmean;
        float vs = gv[c] * rsqrtf(vvar + EPS_);
        vsc[tid] = vs; vsh[tid] = betav[c] - vmean * vs;
    }
    {
        const int rl = tid >> 2, part = tid & 3;
        const unsigned short* qs = qT + ((size_t)b * T_ + t0 + rl) * K_ + part * 16;
        *(bf16x8*)&qTt[rl][part * 16]     = *(const bf16x8*)(qs);
        *(bf16x8*)&qTt[rl][part * 16 + 8] = *(const bf16x8*)(qs + 8);
    }
    {
        const int vl = tid >> 2, qq = tid & 3;
        const int c = v0 + vl;
        float vmean = stat[128 + c] * inv_n;
        float vvar  = stat[384 + c] * inv_n - vmean * vmean;
        float vsv = gv[c] * rsqrtf(vvar + EPS_);
        float vhv = betav[c] - vmean * vsv;
        const float* vrow = v_raw + ((size_t)b * V_ + c) * T_;
        #pragma unroll
        for (int i = 0; i < 22; i++) {
            int cc = qq + 4 * i;
            if (cc < 86) {
                int t = t0 + cc - 11;
                vs2T[cc][vl] = (t >= 0 && t < T_) ? vrow[t] * vsv + vhv : 0.f;
            }
        }
    }
    // clp partial sums: thread owns k-row kk, 16 c's starting at cq
    const int kk = tid >> 2, cq = (tid & 3) * 16;
    float4 a0 = make_float4(0.f,0.f,0.f,0.f), a1 = a0, a2 = a0, a3 = a0;
    #pragma unroll
    for (int tc = 0; tc < NTC_; tc++) {
        const float4* p = (const float4*)(clp + (((size_t)b * NTC_ + tc) * K_ + kk) * V_ + v0 + cq);
        a0.x += p[0].x; a0.y += p[0].y; a0.z += p[0].z; a0.w += p[0].w;
        a1.x += p[1].x; a1.y += p[1].y; a1.z += p[1].z; a1.w += p[1].w;
        a2.x += p[2].x; a2.y += p[2].y; a2.z += p[2].z; a2.w += p[2].w;
        a3.x += p[3].x; a3.y += p[3].y; a3.z += p[3].z; a3.w += p[3].w;
    }
    __syncthreads();

    // ---- stage B: clv writes + hterm wave-reduce; pws/consts fill
    {
        const int lane = tid & 63, w = tid >> 6;
        float av[16];
        *(float4*)&av[0] = a0; *(float4*)&av[4] = a1;
        *(float4*)&av[8] = a2; *(float4*)&av[12] = a3;
        const float qscv = qsc[kk], qshv = qsh[kk];
        #pragma unroll
        for (int i = 0; i < 16; i++) {
            float clbv = av[i] * vsc[cq + i] + vsh[cq + i];
            clv[cq + i][kk] = f2bf(clbv * qscv);
            float h = qshv * clbv;
            h += __shfl_xor(h, 4, 64);
            h += __shfl_xor(h, 8, 64);
            h += __shfl_xor(h, 16, 64);
            h += __shfl_xor(h, 32, 64);
            if (lane < 4) hred[w][lane][i] = h;
        }
    }
    for (int idx = tid; idx < K_ * 24; idx += 256) {
        int k = idx / 24, s = idx % 24;
        pws[k][s] = qsc[k] * (s < KS_ ? pos_w[k * KS_ + s] : pos_b[k]);
    }
    if (tid < 24) {
        float cs = 0.f;
        for (int k = 0; k < K_; k++)
            cs += qsh[k] * (tid < KS_ ? pos_w[k * KS_ + tid] : pos_b[k]);
        consts[tid] = cs;
    }
    __syncthreads();

    // ---- stage C: qpt compute + hvs combine
    if (tid < 64)
        hvs[tid] = hred[0][tid >> 4][tid & 15] + hred[1][tid >> 4][tid & 15]
                 + hred[2][tid >> 4][tid & 15] + hred[3][tid >> 4][tid & 15];
    {
        const int t = tid >> 2, sg = tid & 3, s0 = sg * 6;
        float a[6];
        #pragma unroll
        for (int u = 0; u < 6; u++) a[u] = consts[s0 + u];
        #pragma unroll
        for (int kb = 0; kb < 8; kb++) {
            bf16x8 qv = *(bf16x8*)&qTt[t][kb * 8];
            #pragma unroll
            for (int j = 0; j < 8; j++) {
                float q = bf2f((unsigned short)qv[j]);
                #pragma unroll
                for (int u = 0; u < 6; u++) a[u] += q * pws[kb * 8 + j][s0 + u];
            }
        }
        #pragma unroll
        for (int u = 0; u < 6; u++) qpt[t][s0 + u] = a[u];
    }
    __syncthreads();

    // ---- stage D: content MFMA + conv epilogue
    const int lane = tid & 63, w = tid >> 6;
    const int col = lane & 15, quad = lane >> 4;

    f32x4 acc[4];
    #pragma unroll
    for (int tf = 0; tf < 4; tf++) acc[tf] = (f32x4){0.f, 0.f, 0.f, 0.f};

    #pragma unroll
    for (int ks = 0; ks < 2; ks++) {
        const int kc = ks * 32 + quad * 8;
        bf16x8 af = *(bf16x8*)&clv[w * 16 + col][kc];
        #pragma unroll
        for (int tf = 0; tf < 4; tf++) {
            bf16x8 bq = *(bf16x8*)&qTt[tf * 16 + col][kc];
            acc[tf] = __builtin_amdgcn_mfma_f32_16x16x32_bf16(af, bq, acc[tf], 0, 0, 0);
        }
    }

    const int vb = w * 16 + quad * 4;
    float4 hv4 = *(float4*)&hvs[vb];
    #pragma unroll
    for (int tf = 0; tf < 4; tf++) {
        const int lt = tf * 16 + col;
        float qv[24];
        #pragma unroll
        for (int u = 0; u < 6; u++)
            *(float4*)&qv[4 * u] = *(float4*)&qpt[lt][4 * u];
        float4 a; a.x = acc[tf][0]; a.y = acc[tf][1]; a.z = acc[tf][2]; a.w = acc[tf][3];
        #pragma unroll
        for (int s = 0; s < KS_; s++) {
            float4 wv = *(float4*)&vs2T[lt + s][vb];
            a.x += qv[s] * wv.x; a.y += qv[s] * wv.y;
            a.z += qv[s] * wv.z; a.w += qv[s] * wv.w;
        }
        float base = qv[23];
        a.x += base + hv4.x; a.y += base + hv4.y;
        a.z += base + hv4.z; a.w += base + hv4.w;
        float* ap = (float*)&a;
        #pragma unroll
        for (int r = 0; r < 4; r++)
            out[((size_t)b * V_ + v0 + vb + r) * T_ + t0 + lt] = ap[r];
    }
}

extern "C" void kernel_launch(void* const* d_in, const int* in_sizes, int n_in,
                              void* d_out, int out_size, void* d_ws, size_t ws_size,
                              hipStream_t stream)
{
    const float* x     = (const float*)d_in[0];
    const float* ctx   = (const float*)d_in[1];
    const float* Wq    = (const float*)d_in[2];
    const float* bq    = (const float*)d_in[3];
    const float* Wk    = (const float*)d_in[4];
    const float* bk    = (const float*)d_in[5];
    const float* Wv    = (const float*)d_in[6];
    const float* bv    = (const float*)d_in[7];
    const float* gq    = (const float*)d_in[8];
    const float* betaq = (const float*)d_in[9];
    const float* gv    = (const float*)d_in[10];
    const float* betav = (const float*)d_in[11];
    const float* pos_w = (const float*)d_in[12];
    const float* pos_b = (const float*)d_in[13];
    float* out = (float*)d_out;

    float* ws    = (float*)d_ws;
    float* k_buf = ws;                                   // B*K*T      = 524288
    float* v_raw = k_buf + (size_t)B_ * K_ * T_;         // B*V*T      = 2097152
    float* clp   = v_raw + (size_t)B_ * V_ * T_;         // B*NTC*K*V  = 1048576
    float* stat  = clp + (size_t)B_ * NTC_ * K_ * V_;    // 640
    float* kml   = stat + 640;                           // B*K*8*2 = 8192
    unsigned short* xT   = (unsigned short*)(kml + (size_t)B_ * K_ * 16);
    unsigned short* cT   = xT + (size_t)B_ * T_ * CIN_;
    unsigned short* Wb   = cT + (size_t)B_ * T_ * CIN_;
    unsigned short* qT   = Wb + (size_t)(2 * K_ + V_) * CIN_;

    prep_kernel<<<dim3(2048 + 192), 256, 0, stream>>>(
        x, ctx, Wq, Wk, Wv, xT, cT, Wb, stat);
    proj_mfma6<<<dim3(T_ / 128, 6, B_), 256, 0, stream>>>(
        xT, cT, Wb, bq, bk, bv, k_buf, v_raw, qT, stat, kml);
    lambda_kernel5<<<dim3(NTC_, V_ / 64, B_), 256, 0, stream>>>(k_buf, v_raw, kml, clp);
    out_kernel6<<<dim3(T_ / 64, V_ / 64, B_), 256, 0, stream>>>(
        qT, clp, v_raw, stat, gq, betaq, gv, betav, pos_w, pos_b, out);
}

// Round 6
// 146.244 us; speedup vs baseline: 1.0613x; 1.0499x over previous
//
#include <hip/hip_runtime.h>
#include <math.h>

#define B_ 8
#define CIN_ 512
#define K_ 64
#define V_ 256
#define T_ 1024
#define KS_ 23
#define EPS_ 1e-5f
#define NTC_ 8   // lambda t-chunks (each lambda block accumulates 2 chunks in regs)

typedef __attribute__((ext_vector_type(8))) short bf16x8;
typedef __attribute__((ext_vector_type(4))) float f32x4;

__device__ __forceinline__ unsigned short f2bf(float f) {
    union { float f; unsigned u; } x; x.f = f;
    unsigned r = x.u + 0x7fffu + ((x.u >> 16) & 1u);   // RNE
    return (unsigned short)(r >> 16);
}
__device__ __forceinline__ float bf2f(unsigned short h) {
    union { unsigned u; float f; } x; x.u = ((unsigned)h) << 16;
    return x.f;
}

// async global->LDS, 16B per lane; LDS dest is wave-uniform base + lane*16
__device__ __forceinline__ void gload16(const unsigned short* g, unsigned short* l) {
    __builtin_amdgcn_global_load_lds(
        (const __attribute__((address_space(1))) unsigned int*)(const void*)g,
        (__attribute__((address_space(3))) unsigned int*)(void*)l, 16, 0, 0);
}

// ---------------------------------------------------------------------------
// prep: merged cvtT (blocks 0..2047) + prew (blocks 2048..2239).
// Also zeroes stat[640] + hterm[2048] (contiguous) for downstream atomics.
// ---------------------------------------------------------------------------
__global__ __launch_bounds__(256) void prep_kernel(
    const float* __restrict__ x, const float* __restrict__ ctx,
    const float* __restrict__ Wq, const float* __restrict__ Wk,
    const float* __restrict__ Wv,
    unsigned short* __restrict__ xT, unsigned short* __restrict__ cT,
    unsigned short* __restrict__ Wb, float* __restrict__ stat)
{
    __shared__ unsigned short sh[64][72];
    const int tid = threadIdx.x;
    const int id = blockIdx.x;
    if (id < 2048) {
        const int t0 = (id & 15) * 64, c0 = ((id >> 4) & 7) * 64;
        const int z = id >> 7, b = z & 7, which = z >> 3;
        const float* src = which ? ctx : x;
        unsigned short* dst = which ? cT : xT;
        const int cl = tid >> 2, qq = tid & 3;
        const float* row = src + ((size_t)b * CIN_ + c0 + cl) * T_ + t0 + qq * 16;
        #pragma unroll
        for (int u = 0; u < 4; u++) {
            float4 f = *(const float4*)(row + 4 * u);
            sh[qq * 16 + 4 * u + 0][cl] = f2bf(f.x);
            sh[qq * 16 + 4 * u + 1][cl] = f2bf(f.y);
            sh[qq * 16 + 4 * u + 2][cl] = f2bf(f.z);
            sh[qq * 16 + 4 * u + 3][cl] = f2bf(f.w);
        }
        __syncthreads();
        const int tl = tid >> 2;
        unsigned short* orow = dst + ((size_t)b * T_ + t0 + tl) * CIN_ + c0 + qq * 16;
        *(bf16x8*)(orow)     = *(bf16x8*)&sh[tl][qq * 16];
        *(bf16x8*)(orow + 8) = *(bf16x8*)&sh[tl][qq * 16 + 8];
    } else {
        const int wid = id - 2048;
        if (wid == 0) {
            // zero stat (640 f) + hterm (2048 f) = 672 float4
            #pragma unroll
            for (int i = 0; i < 3; i++) {
                int idx = tid + i * 256;
                if (idx < 672) ((float4*)stat)[idx] = make_float4(0.f, 0.f, 0.f, 0.f);
            }
        }
        const int i4 = wid * 256 + tid;
        const int n1 = K_ * CIN_ / 4, n2 = 2 * K_ * CIN_ / 4;
        const float* src; int off;
        if (i4 < n1)      { src = Wq; off = i4; }
        else if (i4 < n2) { src = Wk; off = i4 - n1; }
        else              { src = Wv; off = i4 - n2; }
        float4 f = ((const float4*)src)[off];
        ushort4 h;
        h.x = f2bf(f.x); h.y = f2bf(f.y); h.z = f2bf(f.z); h.w = f2bf(f.w);
        *(ushort4*)(Wb + (size_t)i4 * 4) = h;
    }
}

// ---------------------------------------------------------------------------
// proj_mfma6 (R3-proven, 148.0): t-tile 128, double-buffered global_load_lds
// staging with counted vmcnt(6). XOR swizzle on BOTH the per-lane global
// source chunk and the MFMA read address.
// ---------------------------------------------------------------------------
__global__ __launch_bounds__(256) void proj_mfma6(
    const unsigned short* __restrict__ xT, const unsigned short* __restrict__ cT,
    const unsigned short* __restrict__ Wb,
    const float* __restrict__ bq, const float* __restrict__ bk,
    const float* __restrict__ bv,
    float* __restrict__ k_buf, float* __restrict__ v_raw,
    unsigned short* __restrict__ qT, float* __restrict__ stat,
    float* __restrict__ kml)
{
    // per buffer: Wt[64][64] (4096 ush) + Xt[128][64] (8192 ush) = 24 KB
    __shared__ __align__(16) unsigned short SMb[2][12288];

    const int tid = threadIdx.x;
    const int b = blockIdx.z, t0 = blockIdx.x * 128, yb = blockIdx.y;

    const unsigned short* in; const unsigned short* W; const float* bias;
    float* outp = nullptr; int ch0 = 0; float* ssum = nullptr; float* ssq = nullptr;
    if (yb == 0)      { in = xT; W = Wb;             bias = bq;
                        ssum = stat; ssq = stat + 64; ch0 = 0; }
    else if (yb == 1) { in = cT; W = Wb + K_ * CIN_; bias = bk;
                        outp = k_buf + (size_t)b * K_ * T_; }
    else { int m0 = (yb - 2) * 64; in = cT;
           W = Wb + 2 * K_ * CIN_ + (size_t)m0 * CIN_; bias = bv + m0;
           outp = v_raw + ((size_t)b * V_ + m0) * T_;
           ssum = stat + 128; ssq = stat + 384; ch0 = m0; }

    const int lane = tid & 63, w = tid >> 6;
    const int col = lane & 15, quad = lane >> 4;

    // staging pointers: chunk g -> row r=g>>3, phys chunk c=g&7 holds
    // global chunk (c ^ (r&7)).  LDS dest base is wave-uniform.
    const int gW0 = (0 * 4 + w) * 64 + lane, rW0 = gW0 >> 3;
    const int gW1 = (1 * 4 + w) * 64 + lane, rW1 = gW1 >> 3;
    const unsigned short* sW0 = W + (size_t)rW0 * CIN_ + (((gW0 & 7) ^ (rW0 & 7)) * 8);
    const unsigned short* sW1 = W + (size_t)rW1 * CIN_ + (((gW1 & 7) ^ (rW1 & 7)) * 8);

    const int gX0 = (0 * 4 + w) * 64 + lane, rX0 = gX0 >> 3;
    const int gX1 = (1 * 4 + w) * 64 + lane, rX1 = gX1 >> 3;
    const int gX2 = (2 * 4 + w) * 64 + lane, rX2 = gX2 >> 3;
    const int gX3 = (3 * 4 + w) * 64 + lane, rX3 = gX3 >> 3;
    const size_t xbase = (size_t)b * T_ + t0;
    const unsigned short* sX0 = in + (xbase + rX0) * CIN_ + (((gX0 & 7) ^ (rX0 & 7)) * 8);
    const unsigned short* sX1 = in + (xbase + rX1) * CIN_ + (((gX1 & 7) ^ (rX1 & 7)) * 8);
    const unsigned short* sX2 = in + (xbase + rX2) * CIN_ + (((gX2 & 7) ^ (rX2 & 7)) * 8);
    const unsigned short* sX3 = in + (xbase + rX3) * CIN_ + (((gX3 & 7) ^ (rX3 & 7)) * 8);

#define STAGE(P, C0) do { \
    unsigned short* Wt_ = SMb[P]; \
    unsigned short* Xt_ = SMb[P] + 4096; \
    gload16(sW0 + (C0), Wt_ + w * 512); \
    gload16(sW1 + (C0), Wt_ + 2048 + w * 512); \
    gload16(sX0 + (C0), Xt_ + w * 512); \
    gload16(sX1 + (C0), Xt_ + 2048 + w * 512); \
    gload16(sX2 + (C0), Xt_ + 4096 + w * 512); \
    gload16(sX3 + (C0), Xt_ + 6144 + w * 512); \
} while (0)

    f32x4 acc[8];
    #pragma unroll
    for (int j = 0; j < 8; j++) acc[j] = (f32x4){0.f, 0.f, 0.f, 0.f};

    STAGE(0, 0);
    for (int s = 0; s < 8; s++) {          // CIN_/64 = 8 K-steps
        const int cur = s & 1;
        if (s < 7) {
            STAGE(cur ^ 1, (s + 1) * 64);
            asm volatile("s_waitcnt vmcnt(6)" ::: "memory");   // current tile done
        } else {
            asm volatile("s_waitcnt vmcnt(0)" ::: "memory");
        }
        __builtin_amdgcn_s_barrier();
        __builtin_amdgcn_sched_barrier(0);
        {
            const unsigned short* Wt = SMb[cur];
            const unsigned short* Xt = SMb[cur] + 4096;
            #pragma unroll
            for (int ks = 0; ks < 2; ks++) {
                const int kc = ((ks * 4 + quad) ^ (col & 7)) * 8;
                bf16x8 af = *(bf16x8*)&Wt[(w * 16 + col) * 64 + kc];
                #pragma unroll
                for (int j = 0; j < 8; j++) {
                    bf16x8 bfr = *(bf16x8*)&Xt[(j * 16 + col) * 64 + kc];
                    acc[j] = __builtin_amdgcn_mfma_f32_16x16x32_bf16(af, bfr, acc[j], 0, 0, 0);
                }
            }
        }
        __builtin_amdgcn_sched_barrier(0);
        __builtin_amdgcn_s_barrier();
    }
#undef STAGE

    float bias_v[4], s_[4], sq[4], mr[4], lr[4];
    #pragma unroll
    for (int r = 0; r < 4; r++) {
        bias_v[r] = bias[w * 16 + quad * 4 + r];
        s_[r] = 0.f; sq[r] = 0.f; mr[r] = -1e30f; lr[r] = 0.f;
    }
    unsigned short* SE = SMb[0];   // epilogue transpose buffer [128][72]
    #pragma unroll
    for (int j = 0; j < 8; j++) {
        float o[4];
        #pragma unroll
        for (int r = 0; r < 4; r++) {
            o[r] = acc[j][r] + bias_v[r];
            s_[r] += o[r]; sq[r] += o[r] * o[r];
        }
        if (yb == 0) {
            ushort4 h;
            h.x = f2bf(o[0]); h.y = f2bf(o[1]); h.z = f2bf(o[2]); h.w = f2bf(o[3]);
            *(ushort4*)&SE[(j * 16 + col) * 72 + w * 16 + quad * 4] = h;
        } else {
            #pragma unroll
            for (int r = 0; r < 4; r++)
                outp[(size_t)(w * 16 + quad * 4 + r) * T_ + t0 + j * 16 + col] = o[r];
            if (yb == 1) {
                #pragma unroll
                for (int r = 0; r < 4; r++) {
                    float mn = fmaxf(mr[r], o[r]);
                    lr[r] = lr[r] * __expf(mr[r] - mn) + __expf(o[r] - mn);
                    mr[r] = mn;
                }
            }
        }
    }
    if (yb == 0) {
        // coalesced qT write: 128 rows x 128B, 64B per thread
        __syncthreads();
        const int tr = tid >> 1, h2 = tid & 1;
        unsigned short* dq = qT + ((size_t)b * T_ + t0 + tr) * K_ + h2 * 32;
        #pragma unroll
        for (int u = 0; u < 4; u++)
            *(bf16x8*)(dq + u * 8) = *(bf16x8*)&SE[tr * 72 + h2 * 32 + u * 8];
    }
    if (yb == 1) {
        // cross-lane online-softmax combine over the 16 cols (same rows)
        #pragma unroll
        for (int r = 0; r < 4; r++) {
            float m = mr[r], l = lr[r];
            #pragma unroll
            for (int off = 1; off < 16; off <<= 1) {
                float mo = __shfl_xor(m, off, 64);
                float lo = __shfl_xor(l, off, 64);
                float mn = fmaxf(m, mo);
                l = l * __expf(m - mn) + lo * __expf(mo - mn);
                m = mn;
            }
            if (col == 0) {
                int row = w * 16 + quad * 4 + r;
                float* p = kml + (((size_t)b * K_ + row) * 8 + (t0 >> 7)) * 2;
                p[0] = m; p[1] = l;
            }
        }
    } else {
        #pragma unroll
        for (int r = 0; r < 4; r++) {
            float sv = s_[r], qv = sq[r];
            #pragma unroll
            for (int off = 1; off < 16; off <<= 1) {
                sv += __shfl_xor(sv, off, 64);
                qv += __shfl_xor(qv, off, 64);
            }
            if (col == 0) {
                int ch = ch0 + w * 16 + quad * 4 + r;
                atomicAdd(&ssum[ch], sv);
                atomicAdd(&ssq[ch], qv);
            }
        }
    }
}

// ---------------------------------------------------------------------------
// lambda5: combine kml partials -> (m, 1/l); each block processes TWO 64-t
// chunks, accumulating in registers -> clp (NTC_=8), no atomics.
// ---------------------------------------------------------------------------
__global__ __launch_bounds__(256) void lambda_kernel5(
    const float* __restrict__ k_buf, const float* __restrict__ v_raw,
    const float* __restrict__ kml, float* __restrict__ clp)
{
    __shared__ __align__(16) float nks[K_][68];
    __shared__ __align__(16) float vls[64][68];
    __shared__ float mrow[64], lrow[64];
    const int tid = threadIdx.x;
    const int b = blockIdx.z, v0 = blockIdx.y * 64, tc = blockIdx.x;

    if (tid < 64) {
        const float2* p = (const float2*)(kml + ((size_t)b * K_ + tid) * 16);
        float m = -1e30f, l = 0.f;
        #pragma unroll
        for (int sgi = 0; sgi < 8; sgi++) {
            float2 ml = p[sgi];
            float mn = fmaxf(m, ml.x);
            l = l * __expf(m - mn) + ml.y * __expf(ml.x - mn);
            m = mn;
        }
        mrow[tid] = m; lrow[tid] = 1.f / l;
    }
    __syncthreads();

    const int r = tid >> 2, q = tid & 3;
    const int tv = tid & 15, tk = tid >> 4;
    float4 acc[4];
    #pragma unroll
    for (int i = 0; i < 4; i++) acc[i] = make_float4(0.f, 0.f, 0.f, 0.f);

    for (int c2 = 0; c2 < 2; c2++) {
        const int t0 = (tc * 2 + c2) * 64;
        if (c2) __syncthreads();           // prior chunk's reads done
        {
            const float* nrow = k_buf + ((size_t)b * K_ + r) * T_ + t0;
            const float* vrow = v_raw + ((size_t)b * V_ + v0 + r) * T_ + t0;
            const float mr = mrow[r], li = lrow[r];
            #pragma unroll
            for (int i = 0; i < 4; i++) {
                int c4 = q + 4 * i;
                float4 g = *(const float4*)(nrow + 4 * c4);
                g.x = __expf(g.x - mr) * li; g.y = __expf(g.y - mr) * li;
                g.z = __expf(g.z - mr) * li; g.w = __expf(g.w - mr) * li;
                *(float4*)&nks[r][4 * c4] = g;
                float4 h = *(const float4*)(vrow + 4 * c4);
                vls[4 * c4 + 0][r] = h.x; vls[4 * c4 + 1][r] = h.y;
                vls[4 * c4 + 2][r] = h.z; vls[4 * c4 + 3][r] = h.w;
            }
        }
        __syncthreads();
        for (int tt = 0; tt < 16; tt++) {
            float4 w0 = *(float4*)&vls[4 * tt + 0][4 * tv];
            float4 w1 = *(float4*)&vls[4 * tt + 1][4 * tv];
            float4 w2 = *(float4*)&vls[4 * tt + 2][4 * tv];
            float4 w3 = *(float4*)&vls[4 * tt + 3][4 * tv];
            #pragma unroll
            for (int i = 0; i < 4; i++) {
                float4 n = *(float4*)&nks[4 * tk + i][4 * tt];
                acc[i] += w0 * n.x + w1 * n.y + w2 * n.z + w3 * n.w;
            }
        }
    }
    #pragma unroll
    for (int i = 0; i < 4; i++)
        *(float4*)&clp[(((size_t)b * NTC_ + tc) * K_ + 4 * tk + i) * V_ + v0 + 4 * tv] = acc[i];
}

// ---------------------------------------------------------------------------
// prep_cl3: sum clp partials; 4-way k-split over blockIdx.z;
// hterm accumulated via atomicAdd (zeroed in prep).
// ---------------------------------------------------------------------------
__global__ __launch_bounds__(256) void prep_cl_kernel3(
    const float* __restrict__ clp, const float* __restrict__ stat,
    const float* __restrict__ gq, const float* __restrict__ betaq,
    const float* __restrict__ gv, const float* __restrict__ betav,
    unsigned short* __restrict__ clb2, float* __restrict__ hterm)
{
    __shared__ float qsc[64], qsh[64], red[4][64];
    const int tid = threadIdx.x;
    const int b = blockIdx.y, v0 = blockIdx.x * 64, kz = blockIdx.z;
    const float inv_n = 1.f / (B_ * T_);
    if (tid < 64) {
        float mean = stat[tid] * inv_n;
        float var  = stat[64 + tid] * inv_n - mean * mean;
        float sc = gq[tid] * rsqrtf(var + EPS_);
        qsc[tid] = sc; qsh[tid] = betaq[tid] - mean * sc;
    }
    const int vl = tid & 63, kq = tid >> 6;
    const int c = v0 + vl;
    float vmean = stat[128 + c] * inv_n;
    float vvar  = stat[384 + c] * inv_n - vmean * vmean;
    float vsv = gv[c] * rsqrtf(vvar + EPS_);
    float vhv = betav[c] - vmean * vsv;
    __syncthreads();
    float h = 0.f;
    #pragma unroll
    for (int kk = 0; kk < 4; kk++) {
        int k = kz * 16 + kq * 4 + kk;
        float a = 0.f;
        #pragma unroll
        for (int tc = 0; tc < NTC_; tc++)
            a += clp[(((size_t)b * NTC_ + tc) * K_ + k) * V_ + c];
        float clbv = a * vsv + vhv;
        h += qsh[k] * clbv;
        clb2[((size_t)b * V_ + c) * K_ + k] = f2bf(clbv * qsc[k]);
    }
    red[kq][vl] = h;
    __syncthreads();
    if (tid < 64)
        atomicAdd(&hterm[(size_t)b * V_ + v0 + tid],
                  red[0][tid] + red[1][tid] + red[2][tid] + red[3][tid]);
}

// ---------------------------------------------------------------------------
// out_kernel7: R3's out5 with stage C (qpt) MFMA-ized.
// qp[t][s] = consts[s] + sum_k q[t][k]*pws[k][s] is a 64x64x24 matmul ->
// 4 MFMAs/wave (was ~384 ds_read_b32 + 384 v_fma per wave).
// pwsT[32][72] bf16 (s-rows, k contiguous) is the B operand; acc is
// initialized with consts[s] broadcast so no post-add is needed.
// ---------------------------------------------------------------------------
__global__ __launch_bounds__(256) void out_kernel7(
    const unsigned short* __restrict__ qT, const unsigned short* __restrict__ clb2,
    const float* __restrict__ hterm, const float* __restrict__ v_raw,
    const float* __restrict__ stat,
    const float* __restrict__ gq, const float* __restrict__ betaq,
    const float* __restrict__ gv, const float* __restrict__ betav,
    const float* __restrict__ pos_w, const float* __restrict__ pos_b,
    float* __restrict__ out)
{
    __shared__ unsigned short qTt[64][72];
    __shared__ unsigned short clv[64][72];
    __shared__ float vs2T[88][68];
    __shared__ float qpt[64][28];
    __shared__ unsigned short pwsT[32][72];
    __shared__ float qsc[64], qsh[64];
    __shared__ float consts[24];
    __shared__ float hvs[64];
    const int tid = threadIdx.x;
    const int b = blockIdx.z, v0 = blockIdx.y * 64, t0 = blockIdx.x * 64;
    const float inv_n = 1.f / (B_ * T_);

    if (tid < 64) {
        float mean = stat[tid] * inv_n;
        float var  = stat[64 + tid] * inv_n - mean * mean;
        float sc = gq[tid] * rsqrtf(var + EPS_);
        qsc[tid] = sc; qsh[tid] = betaq[tid] - mean * sc;
        hvs[tid] = hterm[(size_t)b * V_ + v0 + tid];
    }
    {
        const int rl = tid >> 2, part = tid & 3;
        const unsigned short* qs = qT + ((size_t)b * T_ + t0 + rl) * K_ + part * 16;
        *(bf16x8*)&qTt[rl][part * 16]     = *(const bf16x8*)(qs);
        *(bf16x8*)&qTt[rl][part * 16 + 8] = *(const bf16x8*)(qs + 8);
        const unsigned short* cs = clb2 + ((size_t)b * V_ + v0 + rl) * K_ + part * 16;
        *(bf16x8*)&clv[rl][part * 16]     = *(const bf16x8*)(cs);
        *(bf16x8*)&clv[rl][part * 16 + 8] = *(const bf16x8*)(cs + 8);
    }
    {
        const int vl = tid >> 2, qq = tid & 3;
        const int c = v0 + vl;
        float vmean = stat[128 + c] * inv_n;
        float vvar  = stat[384 + c] * inv_n - vmean * vmean;
        float vsv = gv[c] * rsqrtf(vvar + EPS_);
        float vhv = betav[c] - vmean * vsv;
        const float* vrow = v_raw + ((size_t)b * V_ + c) * T_;
        #pragma unroll
        for (int i = 0; i < 22; i++) {
            int cc = qq + 4 * i;
            if (cc < 86) {
                int t = t0 + cc - 11;
                vs2T[cc][vl] = (t >= 0 && t < T_) ? vrow[t] * vsv + vhv : 0.f;
            }
        }
    }
    __syncthreads();

    // pwsT fill: pwsT[s][k] = bf16(qsc[k] * posw(k,s)); rows 24..31 zero
    for (int idx = tid; idx < 32 * 64; idx += 256) {
        int s = idx >> 6, k = idx & 63;
        float v = (s < KS_) ? pos_w[k * KS_ + s] : (s == KS_ ? pos_b[k] : 0.f);
        pwsT[s][k] = f2bf(qsc[k] * v);
    }
    if (tid < 24) {
        float cs = 0.f;
        for (int k = 0; k < K_; k++)
            cs += qsh[k] * (tid < KS_ ? pos_w[k * KS_ + tid] : pos_b[k]);
        consts[tid] = cs;
    }
    __syncthreads();

    const int lane = tid & 63, w = tid >> 6;
    const int col = lane & 15, quad = lane >> 4;

    // stage C: qpt via MFMA (wave w owns t-tile w*16..w*16+16)
    {
        f32x4 aq[2];
        #pragma unroll
        for (int st = 0; st < 2; st++) {
            int s = st * 16 + col;
            float cv = (s < 24) ? consts[s] : 0.f;
            aq[st] = (f32x4){cv, cv, cv, cv};
        }
        #pragma unroll
        for (int ks = 0; ks < 2; ks++) {
            bf16x8 af = *(bf16x8*)&qTt[w * 16 + col][ks * 32 + quad * 8];
            #pragma unroll
            for (int st = 0; st < 2; st++) {
                bf16x8 bfr = *(bf16x8*)&pwsT[st * 16 + col][ks * 32 + quad * 8];
                aq[st] = __builtin_amdgcn_mfma_f32_16x16x32_bf16(af, bfr, aq[st], 0, 0, 0);
            }
        }
        #pragma unroll
        for (int st = 0; st < 2; st++) {
            int s = st * 16 + col;
            if (s < 24) {
                #pragma unroll
                for (int r = 0; r < 4; r++)
                    qpt[w * 16 + quad * 4 + r][s] = aq[st][r];
            }
        }
    }
    __syncthreads();

    // stage D: content MFMA + conv epilogue
    f32x4 acc[4];
    #pragma unroll
    for (int tf = 0; tf < 4; tf++) acc[tf] = (f32x4){0.f, 0.f, 0.f, 0.f};

    #pragma unroll
    for (int ks = 0; ks < 2; ks++) {
        const int kc = ks * 32 + quad * 8;
        bf16x8 af = *(bf16x8*)&clv[w * 16 + col][kc];
        #pragma unroll
        for (int tf = 0; tf < 4; tf++) {
            bf16x8 bq = *(bf16x8*)&qTt[tf * 16 + col][kc];
            acc[tf] = __builtin_amdgcn_mfma_f32_16x16x32_bf16(af, bq, acc[tf], 0, 0, 0);
        }
    }

    const int vb = w * 16 + quad * 4;
    float4 hv4 = *(float4*)&hvs[vb];
    #pragma unroll
    for (int tf = 0; tf < 4; tf++) {
        const int lt = tf * 16 + col;
        float qv[24];
        #pragma unroll
        for (int u = 0; u < 6; u++)
            *(float4*)&qv[4 * u] = *(float4*)&qpt[lt][4 * u];
        float4 a; a.x = acc[tf][0]; a.y = acc[tf][1]; a.z = acc[tf][2]; a.w = acc[tf][3];
        #pragma unroll
        for (int s = 0; s < KS_; s++) {
            float4 wv = *(float4*)&vs2T[lt + s][vb];
            a.x += qv[s] * wv.x; a.y += qv[s] * wv.y;
            a.z += qv[s] * wv.z; a.w += qv[s] * wv.w;
        }
        float base = qv[23];
        a.x += base + hv4.x; a.y += base + hv4.y;
        a.z += base + hv4.z; a.w += base + hv4.w;
        float* ap = (float*)&a;
        #pragma unroll
        for (int r = 0; r < 4; r++)
            out[((size_t)b * V_ + v0 + vb + r) * T_ + t0 + lt] = ap[r];
    }
}

extern "C" void kernel_launch(void* const* d_in, const int* in_sizes, int n_in,
                              void* d_out, int out_size, void* d_ws, size_t ws_size,
                              hipStream_t stream)
{
    const float* x     = (const float*)d_in[0];
    const float* ctx   = (const float*)d_in[1];
    const float* Wq    = (const float*)d_in[2];
    const float* bq    = (const float*)d_in[3];
    const float* Wk    = (const float*)d_in[4];
    const float* bk    = (const float*)d_in[5];
    const float* Wv    = (const float*)d_in[6];
    const float* bv    = (const float*)d_in[7];
    const float* gq    = (const float*)d_in[8];
    const float* betaq = (const float*)d_in[9];
    const float* gv    = (const float*)d_in[10];
    const float* betav = (const float*)d_in[11];
    const float* pos_w = (const float*)d_in[12];
    const float* pos_b = (const float*)d_in[13];
    float* out = (float*)d_out;

    float* ws    = (float*)d_ws;
    float* k_buf = ws;                                   // B*K*T      = 524288
    float* v_raw = k_buf + (size_t)B_ * K_ * T_;         // B*V*T      = 2097152
    float* clp   = v_raw + (size_t)B_ * V_ * T_;         // B*NTC*K*V  = 1048576
    float* stat  = clp + (size_t)B_ * NTC_ * K_ * V_;    // 640
    float* hterm = stat + 640;                           // B*V = 2048
    float* kml   = hterm + (size_t)B_ * V_;              // B*K*8*2 = 8192
    unsigned short* xT   = (unsigned short*)(kml + (size_t)B_ * K_ * 16);
    unsigned short* cT   = xT + (size_t)B_ * T_ * CIN_;
    unsigned short* Wb   = cT + (size_t)B_ * T_ * CIN_;
    unsigned short* qT   = Wb + (size_t)(2 * K_ + V_) * CIN_;
    unsigned short* clb2 = qT + (size_t)B_ * T_ * K_;

    prep_kernel<<<dim3(2048 + 192), 256, 0, stream>>>(
        x, ctx, Wq, Wk, Wv, xT, cT, Wb, stat);
    proj_mfma6<<<dim3(T_ / 128, 6, B_), 256, 0, stream>>>(
        xT, cT, Wb, bq, bk, bv, k_buf, v_raw, qT, stat, kml);
    lambda_kernel5<<<dim3(NTC_, V_ / 64, B_), 256, 0, stream>>>(k_buf, v_raw, kml, clp);
    prep_cl_kernel3<<<dim3(V_ / 64, B_, 4), 256, 0, stream>>>(
        clp, stat, gq, betaq, gv, betav, clb2, hterm);
    out_kernel7<<<dim3(T_ / 64, V_ / 64, B_), 256, 0, stream>>>(
        qT, clb2, hterm, v_raw, stat, gq, betaq, gv, betav, pos_w, pos_b, out);
}

// Round 7
// 140.870 us; speedup vs baseline: 1.1018x; 1.0382x over previous
//
#include <hip/hip_runtime.h>
#include <math.h>

#define B_ 8
#define CIN_ 512
#define K_ 64
#define V_ 256
#define T_ 1024
#define KS_ 23
#define EPS_ 1e-5f
#define NTC_ 8   // lambda t-chunks (each lambda block accumulates 2 chunks in regs)

typedef __attribute__((ext_vector_type(8))) short bf16x8;
typedef __attribute__((ext_vector_type(4))) float f32x4;

__device__ __forceinline__ unsigned short f2bf(float f) {
    union { float f; unsigned u; } x; x.f = f;
    unsigned r = x.u + 0x7fffu + ((x.u >> 16) & 1u);   // RNE
    return (unsigned short)(r >> 16);
}
__device__ __forceinline__ float bf2f(unsigned short h) {
    union { unsigned u; float f; } x; x.u = ((unsigned)h) << 16;
    return x.f;
}

// async global->LDS, 16B per lane; LDS dest is wave-uniform base + lane*16
__device__ __forceinline__ void gload16(const unsigned short* g, unsigned short* l) {
    __builtin_amdgcn_global_load_lds(
        (const __attribute__((address_space(1))) unsigned int*)(const void*)g,
        (__attribute__((address_space(3))) unsigned int*)(void*)l, 16, 0, 0);
}

// ---------------------------------------------------------------------------
// prep: merged cvtT (blocks 0..2047) + prew (blocks 2048..2239).
// Also zeroes stat[640] + hterm[2048] (contiguous) for downstream atomics.
// ---------------------------------------------------------------------------
__global__ __launch_bounds__(256) void prep_kernel(
    const float* __restrict__ x, const float* __restrict__ ctx,
    const float* __restrict__ Wq, const float* __restrict__ Wk,
    const float* __restrict__ Wv,
    unsigned short* __restrict__ xT, unsigned short* __restrict__ cT,
    unsigned short* __restrict__ Wb, float* __restrict__ stat)
{
    __shared__ unsigned short sh[64][72];
    const int tid = threadIdx.x;
    const int id = blockIdx.x;
    if (id < 2048) {
        const int t0 = (id & 15) * 64, c0 = ((id >> 4) & 7) * 64;
        const int z = id >> 7, b = z & 7, which = z >> 3;
        const float* src = which ? ctx : x;
        unsigned short* dst = which ? cT : xT;
        const int cl = tid >> 2, qq = tid & 3;
        const float* row = src + ((size_t)b * CIN_ + c0 + cl) * T_ + t0 + qq * 16;
        #pragma unroll
        for (int u = 0; u < 4; u++) {
            float4 f = *(const float4*)(row + 4 * u);
            sh[qq * 16 + 4 * u + 0][cl] = f2bf(f.x);
            sh[qq * 16 + 4 * u + 1][cl] = f2bf(f.y);
            sh[qq * 16 + 4 * u + 2][cl] = f2bf(f.z);
            sh[qq * 16 + 4 * u + 3][cl] = f2bf(f.w);
        }
        __syncthreads();
        const int tl = tid >> 2;
        unsigned short* orow = dst + ((size_t)b * T_ + t0 + tl) * CIN_ + c0 + qq * 16;
        *(bf16x8*)(orow)     = *(bf16x8*)&sh[tl][qq * 16];
        *(bf16x8*)(orow + 8) = *(bf16x8*)&sh[tl][qq * 16 + 8];
    } else {
        const int wid = id - 2048;
        if (wid == 0) {
            // zero stat (640 f) + hterm (2048 f) = 672 float4
            #pragma unroll
            for (int i = 0; i < 3; i++) {
                int idx = tid + i * 256;
                if (idx < 672) ((float4*)stat)[idx] = make_float4(0.f, 0.f, 0.f, 0.f);
            }
        }
        const int i4 = wid * 256 + tid;
        const int n1 = K_ * CIN_ / 4, n2 = 2 * K_ * CIN_ / 4;
        const float* src; int off;
        if (i4 < n1)      { src = Wq; off = i4; }
        else if (i4 < n2) { src = Wk; off = i4 - n1; }
        else              { src = Wv; off = i4 - n2; }
        float4 f = ((const float4*)src)[off];
        ushort4 h;
        h.x = f2bf(f.x); h.y = f2bf(f.y); h.z = f2bf(f.z); h.w = f2bf(f.w);
        *(ushort4*)(Wb + (size_t)i4 * 4) = h;
    }
}

// ---------------------------------------------------------------------------
// proj_mfma6 (R3-proven): t-tile 128, double-buffered global_load_lds
// staging with counted vmcnt(6). XOR swizzle on BOTH the per-lane global
// source chunk and the MFMA read address.
// ---------------------------------------------------------------------------
__global__ __launch_bounds__(256) void proj_mfma6(
    const unsigned short* __restrict__ xT, const unsigned short* __restrict__ cT,
    const unsigned short* __restrict__ Wb,
    const float* __restrict__ bq, const float* __restrict__ bk,
    const float* __restrict__ bv,
    float* __restrict__ k_buf, float* __restrict__ v_raw,
    unsigned short* __restrict__ qT, float* __restrict__ stat,
    float* __restrict__ kml)
{
    // per buffer: Wt[64][64] (4096 ush) + Xt[128][64] (8192 ush) = 24 KB
    __shared__ __align__(16) unsigned short SMb[2][12288];

    const int tid = threadIdx.x;
    const int b = blockIdx.z, t0 = blockIdx.x * 128, yb = blockIdx.y;

    const unsigned short* in; const unsigned short* W; const float* bias;
    float* outp = nullptr; int ch0 = 0; float* ssum = nullptr; float* ssq = nullptr;
    if (yb == 0)      { in = xT; W = Wb;             bias = bq;
                        ssum = stat; ssq = stat + 64; ch0 = 0; }
    else if (yb == 1) { in = cT; W = Wb + K_ * CIN_; bias = bk;
                        outp = k_buf + (size_t)b * K_ * T_; }
    else { int m0 = (yb - 2) * 64; in = cT;
           W = Wb + 2 * K_ * CIN_ + (size_t)m0 * CIN_; bias = bv + m0;
           outp = v_raw + ((size_t)b * V_ + m0) * T_;
           ssum = stat + 128; ssq = stat + 384; ch0 = m0; }

    const int lane = tid & 63, w = tid >> 6;
    const int col = lane & 15, quad = lane >> 4;

    // staging pointers: chunk g -> row r=g>>3, phys chunk c=g&7 holds
    // global chunk (c ^ (r&7)).  LDS dest base is wave-uniform.
    const int gW0 = (0 * 4 + w) * 64 + lane, rW0 = gW0 >> 3;
    const int gW1 = (1 * 4 + w) * 64 + lane, rW1 = gW1 >> 3;
    const unsigned short* sW0 = W + (size_t)rW0 * CIN_ + (((gW0 & 7) ^ (rW0 & 7)) * 8);
    const unsigned short* sW1 = W + (size_t)rW1 * CIN_ + (((gW1 & 7) ^ (rW1 & 7)) * 8);

    const int gX0 = (0 * 4 + w) * 64 + lane, rX0 = gX0 >> 3;
    const int gX1 = (1 * 4 + w) * 64 + lane, rX1 = gX1 >> 3;
    const int gX2 = (2 * 4 + w) * 64 + lane, rX2 = gX2 >> 3;
    const int gX3 = (3 * 4 + w) * 64 + lane, rX3 = gX3 >> 3;
    const size_t xbase = (size_t)b * T_ + t0;
    const unsigned short* sX0 = in + (xbase + rX0) * CIN_ + (((gX0 & 7) ^ (rX0 & 7)) * 8);
    const unsigned short* sX1 = in + (xbase + rX1) * CIN_ + (((gX1 & 7) ^ (rX1 & 7)) * 8);
    const unsigned short* sX2 = in + (xbase + rX2) * CIN_ + (((gX2 & 7) ^ (rX2 & 7)) * 8);
    const unsigned short* sX3 = in + (xbase + rX3) * CIN_ + (((gX3 & 7) ^ (rX3 & 7)) * 8);

#define STAGE(P, C0) do { \
    unsigned short* Wt_ = SMb[P]; \
    unsigned short* Xt_ = SMb[P] + 4096; \
    gload16(sW0 + (C0), Wt_ + w * 512); \
    gload16(sW1 + (C0), Wt_ + 2048 + w * 512); \
    gload16(sX0 + (C0), Xt_ + w * 512); \
    gload16(sX1 + (C0), Xt_ + 2048 + w * 512); \
    gload16(sX2 + (C0), Xt_ + 4096 + w * 512); \
    gload16(sX3 + (C0), Xt_ + 6144 + w * 512); \
} while (0)

    f32x4 acc[8];
    #pragma unroll
    for (int j = 0; j < 8; j++) acc[j] = (f32x4){0.f, 0.f, 0.f, 0.f};

    STAGE(0, 0);
    for (int s = 0; s < 8; s++) {          // CIN_/64 = 8 K-steps
        const int cur = s & 1;
        if (s < 7) {
            STAGE(cur ^ 1, (s + 1) * 64);
            asm volatile("s_waitcnt vmcnt(6)" ::: "memory");   // current tile done
        } else {
            asm volatile("s_waitcnt vmcnt(0)" ::: "memory");
        }
        __builtin_amdgcn_s_barrier();
        __builtin_amdgcn_sched_barrier(0);
        {
            const unsigned short* Wt = SMb[cur];
            const unsigned short* Xt = SMb[cur] + 4096;
            #pragma unroll
            for (int ks = 0; ks < 2; ks++) {
                const int kc = ((ks * 4 + quad) ^ (col & 7)) * 8;
                bf16x8 af = *(bf16x8*)&Wt[(w * 16 + col) * 64 + kc];
                #pragma unroll
                for (int j = 0; j < 8; j++) {
                    bf16x8 bfr = *(bf16x8*)&Xt[(j * 16 + col) * 64 + kc];
                    acc[j] = __builtin_amdgcn_mfma_f32_16x16x32_bf16(af, bfr, acc[j], 0, 0, 0);
                }
            }
        }
        __builtin_amdgcn_sched_barrier(0);
        __builtin_amdgcn_s_barrier();
    }
#undef STAGE

    float bias_v[4], s_[4], sq[4], mr[4], lr[4];
    #pragma unroll
    for (int r = 0; r < 4; r++) {
        bias_v[r] = bias[w * 16 + quad * 4 + r];
        s_[r] = 0.f; sq[r] = 0.f; mr[r] = -1e30f; lr[r] = 0.f;
    }
    unsigned short* SE = SMb[0];   // epilogue transpose buffer [128][72]
    #pragma unroll
    for (int j = 0; j < 8; j++) {
        float o[4];
        #pragma unroll
        for (int r = 0; r < 4; r++) {
            o[r] = acc[j][r] + bias_v[r];
            s_[r] += o[r]; sq[r] += o[r] * o[r];
        }
        if (yb == 0) {
            ushort4 h;
            h.x = f2bf(o[0]); h.y = f2bf(o[1]); h.z = f2bf(o[2]); h.w = f2bf(o[3]);
            *(ushort4*)&SE[(j * 16 + col) * 72 + w * 16 + quad * 4] = h;
        } else {
            #pragma unroll
            for (int r = 0; r < 4; r++)
                outp[(size_t)(w * 16 + quad * 4 + r) * T_ + t0 + j * 16 + col] = o[r];
            if (yb == 1) {
                #pragma unroll
                for (int r = 0; r < 4; r++) {
                    float mn = fmaxf(mr[r], o[r]);
                    lr[r] = lr[r] * __expf(mr[r] - mn) + __expf(o[r] - mn);
                    mr[r] = mn;
                }
            }
        }
    }
    if (yb == 0) {
        // coalesced qT write: 128 rows x 128B, 64B per thread
        __syncthreads();
        const int tr = tid >> 1, h2 = tid & 1;
        unsigned short* dq = qT + ((size_t)b * T_ + t0 + tr) * K_ + h2 * 32;
        #pragma unroll
        for (int u = 0; u < 4; u++)
            *(bf16x8*)(dq + u * 8) = *(bf16x8*)&SE[tr * 72 + h2 * 32 + u * 8];
    }
    if (yb == 1) {
        // cross-lane online-softmax combine over the 16 cols (same rows)
        #pragma unroll
        for (int r = 0; r < 4; r++) {
            float m = mr[r], l = lr[r];
            #pragma unroll
            for (int off = 1; off < 16; off <<= 1) {
                float mo = __shfl_xor(m, off, 64);
                float lo = __shfl_xor(l, off, 64);
                float mn = fmaxf(m, mo);
                l = l * __expf(m - mn) + lo * __expf(mo - mn);
                m = mn;
            }
            if (col == 0) {
                int row = w * 16 + quad * 4 + r;
                float* p = kml + (((size_t)b * K_ + row) * 8 + (t0 >> 7)) * 2;
                p[0] = m; p[1] = l;
            }
        }
    } else {
        #pragma unroll
        for (int r = 0; r < 4; r++) {
            float sv = s_[r], qv = sq[r];
            #pragma unroll
            for (int off = 1; off < 16; off <<= 1) {
                sv += __shfl_xor(sv, off, 64);
                qv += __shfl_xor(qv, off, 64);
            }
            if (col == 0) {
                int ch = ch0 + w * 16 + quad * 4 + r;
                atomicAdd(&ssum[ch], sv);
                atomicAdd(&ssq[ch], qv);
            }
        }
    }
}

// ---------------------------------------------------------------------------
// lambda_kernel7: MFMA content-lambda.  nks[k][t], vls[v][t] staged as bf16
// rows (t contiguous, matching global layout -> no transpose), unpadded
// [64][64] tiles with the proj XOR chunk swizzle on write AND read.
// acc[k][v] over K-dim t=128 (2 chunks) via 16 MFMAs/wave; clp unchanged.
// ---------------------------------------------------------------------------
__global__ __launch_bounds__(256) void lambda_kernel7(
    const float* __restrict__ k_buf, const float* __restrict__ v_raw,
    const float* __restrict__ kml, float* __restrict__ clp)
{
    __shared__ __align__(16) unsigned short nks[64][64];
    __shared__ __align__(16) unsigned short vls[64][64];
    __shared__ float mrow[64], lrow[64];
    const int tid = threadIdx.x;
    const int b = blockIdx.z, v0 = blockIdx.y * 64, tc = blockIdx.x;

    if (tid < 64) {
        const float2* p = (const float2*)(kml + ((size_t)b * K_ + tid) * 16);
        float m = -1e30f, l = 0.f;
        #pragma unroll
        for (int sgi = 0; sgi < 8; sgi++) {
            float2 ml = p[sgi];
            float mn = fmaxf(m, ml.x);
            l = l * __expf(m - mn) + ml.y * __expf(ml.x - mn);
            m = mn;
        }
        mrow[tid] = m; lrow[tid] = 1.f / l;
    }
    __syncthreads();

    const int lane = tid & 63, w = tid >> 6;
    const int col = lane & 15, quad = lane >> 4;
    const int r = tid >> 2, q = tid & 3;    // staging: row r (0..63), quarter q

    f32x4 acc[4];
    #pragma unroll
    for (int i = 0; i < 4; i++) acc[i] = (f32x4){0.f, 0.f, 0.f, 0.f};

    for (int c2 = 0; c2 < 2; c2++) {
        const int t0 = (tc * 2 + c2) * 64;
        if (c2) __syncthreads();           // prior chunk's reads done
        {
            const float* nrow = k_buf + ((size_t)b * K_ + r) * T_ + t0;
            const float* vrow = v_raw + ((size_t)b * V_ + v0 + r) * T_ + t0;
            const float mr = mrow[r], li = lrow[r];
            #pragma unroll
            for (int i = 0; i < 2; i++) {
                const int c8 = q + 4 * i;                // 8-t chunk 0..7
                const int sc = (c8 ^ (r & 7)) * 8;       // swizzled LDS col
                float4 g0 = *(const float4*)(nrow + 8 * c8);
                float4 g1 = *(const float4*)(nrow + 8 * c8 + 4);
                ushort4 k0, k1;
                k0.x = f2bf(__expf(g0.x - mr) * li); k0.y = f2bf(__expf(g0.y - mr) * li);
                k0.z = f2bf(__expf(g0.z - mr) * li); k0.w = f2bf(__expf(g0.w - mr) * li);
                k1.x = f2bf(__expf(g1.x - mr) * li); k1.y = f2bf(__expf(g1.y - mr) * li);
                k1.z = f2bf(__expf(g1.z - mr) * li); k1.w = f2bf(__expf(g1.w - mr) * li);
                *(ushort4*)&nks[r][sc]     = k0;
                *(ushort4*)&nks[r][sc + 4] = k1;
                float4 h0 = *(const float4*)(vrow + 8 * c8);
                float4 h1 = *(const float4*)(vrow + 8 * c8 + 4);
                ushort4 v0v, v1v;
                v0v.x = f2bf(h0.x); v0v.y = f2bf(h0.y); v0v.z = f2bf(h0.z); v0v.w = f2bf(h0.w);
                v1v.x = f2bf(h1.x); v1v.y = f2bf(h1.y); v1v.z = f2bf(h1.z); v1v.w = f2bf(h1.w);
                *(ushort4*)&vls[r][sc]     = v0v;
                *(ushort4*)&vls[r][sc + 4] = v1v;
            }
        }
        __syncthreads();
        #pragma unroll
        for (int ks = 0; ks < 2; ks++) {
            const int kc = ((ks * 4 + quad) ^ (col & 7)) * 8;
            bf16x8 af = *(bf16x8*)&nks[w * 16 + col][kc];
            #pragma unroll
            for (int vt = 0; vt < 4; vt++) {
                bf16x8 bfr = *(bf16x8*)&vls[vt * 16 + col][kc];
                acc[vt] = __builtin_amdgcn_mfma_f32_16x16x32_bf16(af, bfr, acc[vt], 0, 0, 0);
            }
        }
    }
    // write: k = w*16 + quad*4 + rr (A-rows), v = vt*16 + col (B-rows)
    float* dst = clp + (((size_t)b * NTC_ + tc) * K_ + (w * 16 + quad * 4)) * V_ + v0;
    #pragma unroll
    for (int vt = 0; vt < 4; vt++)
        #pragma unroll
        for (int rr = 0; rr < 4; rr++)
            dst[(size_t)rr * V_ + vt * 16 + col] = acc[vt][rr];
}

// ---------------------------------------------------------------------------
// prep_cl3: sum clp partials; 4-way k-split over blockIdx.z;
// hterm accumulated via atomicAdd (zeroed in prep).
// ---------------------------------------------------------------------------
__global__ __launch_bounds__(256) void prep_cl_kernel3(
    const float* __restrict__ clp, const float* __restrict__ stat,
    const float* __restrict__ gq, const float* __restrict__ betaq,
    const float* __restrict__ gv, const float* __restrict__ betav,
    unsigned short* __restrict__ clb2, float* __restrict__ hterm)
{
    __shared__ float qsc[64], qsh[64], red[4][64];
    const int tid = threadIdx.x;
    const int b = blockIdx.y, v0 = blockIdx.x * 64, kz = blockIdx.z;
    const float inv_n = 1.f / (B_ * T_);
    if (tid < 64) {
        float mean = stat[tid] * inv_n;
        float var  = stat[64 + tid] * inv_n - mean * mean;
        float sc = gq[tid] * rsqrtf(var + EPS_);
        qsc[tid] = sc; qsh[tid] = betaq[tid] - mean * sc;
    }
    const int vl = tid & 63, kq = tid >> 6;
    const int c = v0 + vl;
    float vmean = stat[128 + c] * inv_n;
    float vvar  = stat[384 + c] * inv_n - vmean * vmean;
    float vsv = gv[c] * rsqrtf(vvar + EPS_);
    float vhv = betav[c] - vmean * vsv;
    __syncthreads();
    float h = 0.f;
    #pragma unroll
    for (int kk = 0; kk < 4; kk++) {
        int k = kz * 16 + kq * 4 + kk;
        float a = 0.f;
        #pragma unroll
        for (int tc = 0; tc < NTC_; tc++)
            a += clp[(((size_t)b * NTC_ + tc) * K_ + k) * V_ + c];
        float clbv = a * vsv + vhv;
        h += qsh[k] * clbv;
        clb2[((size_t)b * V_ + c) * K_ + k] = f2bf(clbv * qsc[k]);
    }
    red[kq][vl] = h;
    __syncthreads();
    if (tid < 64)
        atomicAdd(&hterm[(size_t)b * V_ + v0 + tid],
                  red[0][tid] + red[1][tid] + red[2][tid] + red[3][tid]);
}

// ---------------------------------------------------------------------------
// out_kernel7 (R6-proven): MFMA-ized qpt stage + content MFMA + conv epilogue.
// ---------------------------------------------------------------------------
__global__ __launch_bounds__(256) void out_kernel7(
    const unsigned short* __restrict__ qT, const unsigned short* __restrict__ clb2,
    const float* __restrict__ hterm, const float* __restrict__ v_raw,
    const float* __restrict__ stat,
    const float* __restrict__ gq, const float* __restrict__ betaq,
    const float* __restrict__ gv, const float* __restrict__ betav,
    const float* __restrict__ pos_w, const float* __restrict__ pos_b,
    float* __restrict__ out)
{
    __shared__ unsigned short qTt[64][72];
    __shared__ unsigned short clv[64][72];
    __shared__ float vs2T[88][68];
    __shared__ float qpt[64][28];
    __shared__ unsigned short pwsT[32][72];
    __shared__ float qsc[64], qsh[64];
    __shared__ float consts[24];
    __shared__ float hvs[64];
    const int tid = threadIdx.x;
    const int b = blockIdx.z, v0 = blockIdx.y * 64, t0 = blockIdx.x * 64;
    const float inv_n = 1.f / (B_ * T_);

    if (tid < 64) {
        float mean = stat[tid] * inv_n;
        float var  = stat[64 + tid] * inv_n - mean * mean;
        float sc = gq[tid] * rsqrtf(var + EPS_);
        qsc[tid] = sc; qsh[tid] = betaq[tid] - mean * sc;
        hvs[tid] = hterm[(size_t)b * V_ + v0 + tid];
    }
    {
        const int rl = tid >> 2, part = tid & 3;
        const unsigned short* qs = qT + ((size_t)b * T_ + t0 + rl) * K_ + part * 16;
        *(bf16x8*)&qTt[rl][part * 16]     = *(const bf16x8*)(qs);
        *(bf16x8*)&qTt[rl][part * 16 + 8] = *(const bf16x8*)(qs + 8);
        const unsigned short* cs = clb2 + ((size_t)b * V_ + v0 + rl) * K_ + part * 16;
        *(bf16x8*)&clv[rl][part * 16]     = *(const bf16x8*)(cs);
        *(bf16x8*)&clv[rl][part * 16 + 8] = *(const bf16x8*)(cs + 8);
    }
    {
        const int vl = tid >> 2, qq = tid & 3;
        const int c = v0 + vl;
        float vmean = stat[128 + c] * inv_n;
        float vvar  = stat[384 + c] * inv_n - vmean * vmean;
        float vsv = gv[c] * rsqrtf(vvar + EPS_);
        float vhv = betav[c] - vmean * vsv;
        const float* vrow = v_raw + ((size_t)b * V_ + c) * T_;
        #pragma unroll
        for (int i = 0; i < 22; i++) {
            int cc = qq + 4 * i;
            if (cc < 86) {
                int t = t0 + cc - 11;
                vs2T[cc][vl] = (t >= 0 && t < T_) ? vrow[t] * vsv + vhv : 0.f;
            }
        }
    }
    __syncthreads();

    // pwsT fill: pwsT[s][k] = bf16(qsc[k] * posw(k,s)); rows 24..31 zero
    for (int idx = tid; idx < 32 * 64; idx += 256) {
        int s = idx >> 6, k = idx & 63;
        float v = (s < KS_) ? pos_w[k * KS_ + s] : (s == KS_ ? pos_b[k] : 0.f);
        pwsT[s][k] = f2bf(qsc[k] * v);
    }
    if (tid < 24) {
        float cs = 0.f;
        for (int k = 0; k < K_; k++)
            cs += qsh[k] * (tid < KS_ ? pos_w[k * KS_ + tid] : pos_b[k]);
        consts[tid] = cs;
    }
    __syncthreads();

    const int lane = tid & 63, w = tid >> 6;
    const int col = lane & 15, quad = lane >> 4;

    // stage C: qpt via MFMA (wave w owns t-tile w*16..w*16+16)
    {
        f32x4 aq[2];
        #pragma unroll
        for (int st = 0; st < 2; st++) {
            int s = st * 16 + col;
            float cv = (s < 24) ? consts[s] : 0.f;
            aq[st] = (f32x4){cv, cv, cv, cv};
        }
        #pragma unroll
        for (int ks = 0; ks < 2; ks++) {
            bf16x8 af = *(bf16x8*)&qTt[w * 16 + col][ks * 32 + quad * 8];
            #pragma unroll
            for (int st = 0; st < 2; st++) {
                bf16x8 bfr = *(bf16x8*)&pwsT[st * 16 + col][ks * 32 + quad * 8];
                aq[st] = __builtin_amdgcn_mfma_f32_16x16x32_bf16(af, bfr, aq[st], 0, 0, 0);
            }
        }
        #pragma unroll
        for (int st = 0; st < 2; st++) {
            int s = st * 16 + col;
            if (s < 24) {
                #pragma unroll
                for (int r = 0; r < 4; r++)
                    qpt[w * 16 + quad * 4 + r][s] = aq[st][r];
            }
        }
    }
    __syncthreads();

    // stage D: content MFMA + conv epilogue
    f32x4 acc[4];
    #pragma unroll
    for (int tf = 0; tf < 4; tf++) acc[tf] = (f32x4){0.f, 0.f, 0.f, 0.f};

    #pragma unroll
    for (int ks = 0; ks < 2; ks++) {
        const int kc = ks * 32 + quad * 8;
        bf16x8 af = *(bf16x8*)&clv[w * 16 + col][kc];
        #pragma unroll
        for (int tf = 0; tf < 4; tf++) {
            bf16x8 bq = *(bf16x8*)&qTt[tf * 16 + col][kc];
            acc[tf] = __builtin_amdgcn_mfma_f32_16x16x32_bf16(af, bq, acc[tf], 0, 0, 0);
        }
    }

    const int vb = w * 16 + quad * 4;
    float4 hv4 = *(float4*)&hvs[vb];
    #pragma unroll
    for (int tf = 0; tf < 4; tf++) {
        const int lt = tf * 16 + col;
        float qv[24];
        #pragma unroll
        for (int u = 0; u < 6; u++)
            *(float4*)&qv[4 * u] = *(float4*)&qpt[lt][4 * u];
        float4 a; a.x = acc[tf][0]; a.y = acc[tf][1]; a.z = acc[tf][2]; a.w = acc[tf][3];
        #pragma unroll
        for (int s = 0; s < KS_; s++) {
            float4 wv = *(float4*)&vs2T[lt + s][vb];
            a.x += qv[s] * wv.x; a.y += qv[s] * wv.y;
            a.z += qv[s] * wv.z; a.w += qv[s] * wv.w;
        }
        float base = qv[23];
        a.x += base + hv4.x; a.y += base + hv4.y;
        a.z += base + hv4.z; a.w += base + hv4.w;
        float* ap = (float*)&a;
        #pragma unroll
        for (int r = 0; r < 4; r++)
            out[((size_t)b * V_ + v0 + vb + r) * T_ + t0 + lt] = ap[r];
    }
}

extern "C" void kernel_launch(void* const* d_in, const int* in_sizes, int n_in,
                              void* d_out, int out_size, void* d_ws, size_t ws_size,
                              hipStream_t stream)
{
    const float* x     = (const float*)d_in[0];
    const float* ctx   = (const float*)d_in[1];
    const float* Wq    = (const float*)d_in[2];
    const float* bq    = (const float*)d_in[3];
    const float* Wk    = (const float*)d_in[4];
    const float* bk    = (const float*)d_in[5];
    const float* Wv    = (const float*)d_in[6];
    const float* bv    = (const float*)d_in[7];
    const float* gq    = (const float*)d_in[8];
    const float* betaq = (const float*)d_in[9];
    const float* gv    = (const float*)d_in[10];
    const float* betav = (const float*)d_in[11];
    const float* pos_w = (const float*)d_in[12];
    const float* pos_b = (const float*)d_in[13];
    float* out = (float*)d_out;

    float* ws    = (float*)d_ws;
    float* k_buf = ws;                                   // B*K*T      = 524288
    float* v_raw = k_buf + (size_t)B_ * K_ * T_;         // B*V*T      = 2097152
    float* clp   = v_raw + (size_t)B_ * V_ * T_;         // B*NTC*K*V  = 1048576
    float* stat  = clp + (size_t)B_ * NTC_ * K_ * V_;    // 640
    float* hterm = stat + 640;                           // B*V = 2048
    float* kml   = hterm + (size_t)B_ * V_;              // B*K*8*2 = 8192
    unsigned short* xT   = (unsigned short*)(kml + (size_t)B_ * K_ * 16);
    unsigned short* cT   = xT + (size_t)B_ * T_ * CIN_;
    unsigned short* Wb   = cT + (size_t)B_ * T_ * CIN_;
    unsigned short* qT   = Wb + (size_t)(2 * K_ + V_) * CIN_;
    unsigned short* clb2 = qT + (size_t)B_ * T_ * K_;

    prep_kernel<<<dim3(2048 + 192), 256, 0, stream>>>(
        x, ctx, Wq, Wk, Wv, xT, cT, Wb, stat);
    proj_mfma6<<<dim3(T_ / 128, 6, B_), 256, 0, stream>>>(
        xT, cT, Wb, bq, bk, bv, k_buf, v_raw, qT, stat, kml);
    lambda_kernel7<<<dim3(NTC_, V_ / 64, B_), 256, 0, stream>>>(k_buf, v_raw, kml, clp);
    prep_cl_kernel3<<<dim3(V_ / 64, B_, 4), 256, 0, stream>>>(
        clp, stat, gq, betaq, gv, betav, clb2, hterm);
    out_kernel7<<<dim3(T_ / 64, V_ / 64, B_), 256, 0, stream>>>(
        qT, clb2, hterm, v_raw, stat, gq, betaq, gv, betav, pos_w, pos_b, out);
}

// Round 10
// 139.053 us; speedup vs baseline: 1.1162x; 1.0131x over previous
//
#include <hip/hip_runtime.h>
#include <math.h>

#define B_ 8
#define CIN_ 512
#define K_ 64
#define V_ 256
#define T_ 1024
#define KS_ 23
#define EPS_ 1e-5f
#define NTC_ 8   // lambda t-chunks (each lambda block accumulates 2 chunks in regs)

typedef __attribute__((ext_vector_type(8))) short bf16x8;
typedef __attribute__((ext_vector_type(4))) float f32x4;

__device__ __forceinline__ unsigned short f2bf(float f) {
    union { float f; unsigned u; } x; x.f = f;
    unsigned r = x.u + 0x7fffu + ((x.u >> 16) & 1u);   // RNE
    return (unsigned short)(r >> 16);
}
__device__ __forceinline__ float bf2f(unsigned short h) {
    union { unsigned u; float f; } x; x.u = ((unsigned)h) << 16;
    return x.f;
}

// async global->LDS, 16B per lane; LDS dest MUST be wave-uniform (HW adds
// lane*16 itself); per-lane variation belongs on the global source only.
__device__ __forceinline__ void gload16(const unsigned short* g, unsigned short* l) {
    __builtin_amdgcn_global_load_lds(
        (const __attribute__((address_space(1))) unsigned int*)(const void*)g,
        (__attribute__((address_space(3))) unsigned int*)(void*)l, 16, 0, 0);
}

// ---------------------------------------------------------------------------
// prep: merged cvtT (blocks 0..2047) + prew (blocks 2048..2239).
// Also zeroes stat[640] + hterm[2048] (contiguous) for downstream atomics.
// ---------------------------------------------------------------------------
__global__ __launch_bounds__(256) void prep_kernel(
    const float* __restrict__ x, const float* __restrict__ ctx,
    const float* __restrict__ Wq, const float* __restrict__ Wk,
    const float* __restrict__ Wv,
    unsigned short* __restrict__ xT, unsigned short* __restrict__ cT,
    unsigned short* __restrict__ Wb, float* __restrict__ stat)
{
    __shared__ unsigned short sh[64][72];
    const int tid = threadIdx.x;
    const int id = blockIdx.x;
    if (id < 2048) {
        const int t0 = (id & 15) * 64, c0 = ((id >> 4) & 7) * 64;
        const int z = id >> 7, b = z & 7, which = z >> 3;
        const float* src = which ? ctx : x;
        unsigned short* dst = which ? cT : xT;
        const int cl = tid >> 2, qq = tid & 3;
        const float* row = src + ((size_t)b * CIN_ + c0 + cl) * T_ + t0 + qq * 16;
        #pragma unroll
        for (int u = 0; u < 4; u++) {
            float4 f = *(const float4*)(row + 4 * u);
            sh[qq * 16 + 4 * u + 0][cl] = f2bf(f.x);
            sh[qq * 16 + 4 * u + 1][cl] = f2bf(f.y);
            sh[qq * 16 + 4 * u + 2][cl] = f2bf(f.z);
            sh[qq * 16 + 4 * u + 3][cl] = f2bf(f.w);
        }
        __syncthreads();
        const int tl = tid >> 2;
        unsigned short* orow = dst + ((size_t)b * T_ + t0 + tl) * CIN_ + c0 + qq * 16;
        *(bf16x8*)(orow)     = *(bf16x8*)&sh[tl][qq * 16];
        *(bf16x8*)(orow + 8) = *(bf16x8*)&sh[tl][qq * 16 + 8];
    } else {
        const int wid = id - 2048;
        if (wid == 0) {
            // zero stat (640 f) + hterm (2048 f) = 672 float4
            #pragma unroll
            for (int i = 0; i < 3; i++) {
                int idx = tid + i * 256;
                if (idx < 672) ((float4*)stat)[idx] = make_float4(0.f, 0.f, 0.f, 0.f);
            }
        }
        const int i4 = wid * 256 + tid;
        const int n1 = K_ * CIN_ / 4, n2 = 2 * K_ * CIN_ / 4;
        const float* src; int off;
        if (i4 < n1)      { src = Wq; off = i4; }
        else if (i4 < n2) { src = Wk; off = i4 - n1; }
        else              { src = Wv; off = i4 - n2; }
        float4 f = ((const float4*)src)[off];
        ushort4 h;
        h.x = f2bf(f.x); h.y = f2bf(f.y); h.z = f2bf(f.z); h.w = f2bf(f.w);
        *(ushort4*)(Wb + (size_t)i4 * 4) = h;
    }
}

// ---------------------------------------------------------------------------
// proj_mfma8: R3-proven pipeline; v output bf16 (k stays fp32 raw for
// exact softmax partials).
// ---------------------------------------------------------------------------
__global__ __launch_bounds__(256) void proj_mfma8(
    const unsigned short* __restrict__ xT, const unsigned short* __restrict__ cT,
    const unsigned short* __restrict__ Wb,
    const float* __restrict__ bq, const float* __restrict__ bk,
    const float* __restrict__ bv,
    float* __restrict__ k_buf, unsigned short* __restrict__ v_raw,
    unsigned short* __restrict__ qT, float* __restrict__ stat,
    float* __restrict__ kml)
{
    // per buffer: Wt[64][64] (4096 ush) + Xt[128][64] (8192 ush) = 24 KB
    __shared__ __align__(16) unsigned short SMb[2][12288];

    const int tid = threadIdx.x;
    const int b = blockIdx.z, t0 = blockIdx.x * 128, yb = blockIdx.y;

    const unsigned short* in; const unsigned short* W; const float* bias;
    float* koutp = nullptr; unsigned short* voutp = nullptr;
    int ch0 = 0; float* ssum = nullptr; float* ssq = nullptr;
    if (yb == 0)      { in = xT; W = Wb;             bias = bq;
                        ssum = stat; ssq = stat + 64; ch0 = 0; }
    else if (yb == 1) { in = cT; W = Wb + K_ * CIN_; bias = bk;
                        koutp = k_buf + (size_t)b * K_ * T_; }
    else { int m0 = (yb - 2) * 64; in = cT;
           W = Wb + 2 * K_ * CIN_ + (size_t)m0 * CIN_; bias = bv + m0;
           voutp = v_raw + ((size_t)b * V_ + m0) * T_;
           ssum = stat + 128; ssq = stat + 384; ch0 = m0; }

    const int lane = tid & 63, w = tid >> 6;
    const int col = lane & 15, quad = lane >> 4;

    // staging pointers: chunk g -> row r=g>>3, phys chunk c=g&7 holds
    // global chunk (c ^ (r&7)).  LDS dest base is wave-uniform.
    const int gW0 = (0 * 4 + w) * 64 + lane, rW0 = gW0 >> 3;
    const int gW1 = (1 * 4 + w) * 64 + lane, rW1 = gW1 >> 3;
    const unsigned short* sW0 = W + (size_t)rW0 * CIN_ + (((gW0 & 7) ^ (rW0 & 7)) * 8);
    const unsigned short* sW1 = W + (size_t)rW1 * CIN_ + (((gW1 & 7) ^ (rW1 & 7)) * 8);

    const int gX0 = (0 * 4 + w) * 64 + lane, rX0 = gX0 >> 3;
    const int gX1 = (1 * 4 + w) * 64 + lane, rX1 = gX1 >> 3;
    const int gX2 = (2 * 4 + w) * 64 + lane, rX2 = gX2 >> 3;
    const int gX3 = (3 * 4 + w) * 64 + lane, rX3 = gX3 >> 3;
    const size_t xbase = (size_t)b * T_ + t0;
    const unsigned short* sX0 = in + (xbase + rX0) * CIN_ + (((gX0 & 7) ^ (rX0 & 7)) * 8);
    const unsigned short* sX1 = in + (xbase + rX1) * CIN_ + (((gX1 & 7) ^ (rX1 & 7)) * 8);
    const unsigned short* sX2 = in + (xbase + rX2) * CIN_ + (((gX2 & 7) ^ (rX2 & 7)) * 8);
    const unsigned short* sX3 = in + (xbase + rX3) * CIN_ + (((gX3 & 7) ^ (rX3 & 7)) * 8);

#define STAGE(P, C0) do { \
    unsigned short* Wt_ = SMb[P]; \
    unsigned short* Xt_ = SMb[P] + 4096; \
    gload16(sW0 + (C0), Wt_ + w * 512); \
    gload16(sW1 + (C0), Wt_ + 2048 + w * 512); \
    gload16(sX0 + (C0), Xt_ + w * 512); \
    gload16(sX1 + (C0), Xt_ + 2048 + w * 512); \
    gload16(sX2 + (C0), Xt_ + 4096 + w * 512); \
    gload16(sX3 + (C0), Xt_ + 6144 + w * 512); \
} while (0)

    f32x4 acc[8];
    #pragma unroll
    for (int j = 0; j < 8; j++) acc[j] = (f32x4){0.f, 0.f, 0.f, 0.f};

    STAGE(0, 0);
    for (int s = 0; s < 8; s++) {          // CIN_/64 = 8 K-steps
        const int cur = s & 1;
        if (s < 7) {
            STAGE(cur ^ 1, (s + 1) * 64);
            asm volatile("s_waitcnt vmcnt(6)" ::: "memory");   // current tile done
        } else {
            asm volatile("s_waitcnt vmcnt(0)" ::: "memory");
        }
        __builtin_amdgcn_s_barrier();
        __builtin_amdgcn_sched_barrier(0);
        {
            const unsigned short* Wt = SMb[cur];
            const unsigned short* Xt = SMb[cur] + 4096;
            #pragma unroll
            for (int ks = 0; ks < 2; ks++) {
                const int kc = ((ks * 4 + quad) ^ (col & 7)) * 8;
                bf16x8 af = *(bf16x8*)&Wt[(w * 16 + col) * 64 + kc];
                #pragma unroll
                for (int j = 0; j < 8; j++) {
                    bf16x8 bfr = *(bf16x8*)&Xt[(j * 16 + col) * 64 + kc];
                    acc[j] = __builtin_amdgcn_mfma_f32_16x16x32_bf16(af, bfr, acc[j], 0, 0, 0);
                }
            }
        }
        __builtin_amdgcn_sched_barrier(0);
        __builtin_amdgcn_s_barrier();
    }
#undef STAGE

    float bias_v[4], s_[4], sq[4], mr[4], lr[4];
    #pragma unroll
    for (int r = 0; r < 4; r++) {
        bias_v[r] = bias[w * 16 + quad * 4 + r];
        s_[r] = 0.f; sq[r] = 0.f; mr[r] = -1e30f; lr[r] = 0.f;
    }
    unsigned short* SE = SMb[0];   // epilogue transpose buffer [128][72]
    #pragma unroll
    for (int j = 0; j < 8; j++) {
        float o[4];
        #pragma unroll
        for (int r = 0; r < 4; r++) {
            o[r] = acc[j][r] + bias_v[r];
            s_[r] += o[r]; sq[r] += o[r] * o[r];
        }
        if (yb == 0) {
            ushort4 h;
            h.x = f2bf(o[0]); h.y = f2bf(o[1]); h.z = f2bf(o[2]); h.w = f2bf(o[3]);
            *(ushort4*)&SE[(j * 16 + col) * 72 + w * 16 + quad * 4] = h;
        } else if (yb == 1) {
            #pragma unroll
            for (int r = 0; r < 4; r++) {
                koutp[(size_t)(w * 16 + quad * 4 + r) * T_ + t0 + j * 16 + col] = o[r];
                float mn = fmaxf(mr[r], o[r]);
                lr[r] = lr[r] * __expf(mr[r] - mn) + __expf(o[r] - mn);
                mr[r] = mn;
            }
        } else {
            #pragma unroll
            for (int r = 0; r < 4; r++)
                voutp[(size_t)(w * 16 + quad * 4 + r) * T_ + t0 + j * 16 + col] = f2bf(o[r]);
        }
    }
    if (yb == 0) {
        // coalesced qT write: 128 rows x 128B, 64B per thread
        __syncthreads();
        const int tr = tid >> 1, h2 = tid & 1;
        unsigned short* dq = qT + ((size_t)b * T_ + t0 + tr) * K_ + h2 * 32;
        #pragma unroll
        for (int u = 0; u < 4; u++)
            *(bf16x8*)(dq + u * 8) = *(bf16x8*)&SE[tr * 72 + h2 * 32 + u * 8];
    }
    if (yb == 1) {
        // cross-lane online-softmax combine over the 16 cols (same rows)
        #pragma unroll
        for (int r = 0; r < 4; r++) {
            float m = mr[r], l = lr[r];
            #pragma unroll
            for (int off = 1; off < 16; off <<= 1) {
                float mo = __shfl_xor(m, off, 64);
                float lo = __shfl_xor(l, off, 64);
                float mn = fmaxf(m, mo);
                l = l * __expf(m - mn) + lo * __expf(mo - mn);
                m = mn;
            }
            if (col == 0) {
                int row = w * 16 + quad * 4 + r;
                float* p = kml + (((size_t)b * K_ + row) * 8 + (t0 >> 7)) * 2;
                p[0] = m; p[1] = l;
            }
        }
    } else {
        #pragma unroll
        for (int r = 0; r < 4; r++) {
            float sv = s_[r], qv = sq[r];
            #pragma unroll
            for (int off = 1; off < 16; off <<= 1) {
                sv += __shfl_xor(sv, off, 64);
                qv += __shfl_xor(qv, off, 64);
            }
            if (col == 0) {
                int ch = ch0 + w * 16 + quad * 4 + r;
                atomicAdd(&ssum[ch], sv);
                atomicAdd(&ssq[ch], qv);
            }
        }
    }
}

// ---------------------------------------------------------------------------
// lambda_kernel10: R7's PROVEN MFMA content-lambda with manual staging;
// only change: v input is bf16 (direct ushort4 copy, no f2bf).
// ---------------------------------------------------------------------------
__global__ __launch_bounds__(256) void lambda_kernel10(
    const float* __restrict__ k_buf, const unsigned short* __restrict__ v_raw,
    const float* __restrict__ kml, float* __restrict__ clp)
{
    __shared__ __align__(16) unsigned short nks[64][64];
    __shared__ __align__(16) unsigned short vls[64][64];
    __shared__ float mrow[64], lrow[64];
    const int tid = threadIdx.x;
    const int b = blockIdx.z, v0 = blockIdx.y * 64, tc = blockIdx.x;

    if (tid < 64) {
        const float2* p = (const float2*)(kml + ((size_t)b * K_ + tid) * 16);
        float m = -1e30f, l = 0.f;
        #pragma unroll
        for (int sgi = 0; sgi < 8; sgi++) {
            float2 ml = p[sgi];
            float mn = fmaxf(m, ml.x);
            l = l * __expf(m - mn) + ml.y * __expf(ml.x - mn);
            m = mn;
        }
        mrow[tid] = m; lrow[tid] = 1.f / l;
    }
    __syncthreads();

    const int lane = tid & 63, w = tid >> 6;
    const int col = lane & 15, quad = lane >> 4;
    const int r = tid >> 2, q = tid & 3;    // staging: row r (0..63), quarter q

    f32x4 acc[4];
    #pragma unroll
    for (int i = 0; i < 4; i++) acc[i] = (f32x4){0.f, 0.f, 0.f, 0.f};

    for (int c2 = 0; c2 < 2; c2++) {
        const int t0 = (tc * 2 + c2) * 64;
        if (c2) __syncthreads();           // prior chunk's reads done
        {
            const float* nrow = k_buf + ((size_t)b * K_ + r) * T_ + t0;
            const unsigned short* vrow = v_raw + ((size_t)b * V_ + v0 + r) * T_ + t0;
            const float mr = mrow[r], li = lrow[r];
            #pragma unroll
            for (int i = 0; i < 2; i++) {
                const int c8 = q + 4 * i;                // 8-t chunk 0..7
                const int sc = (c8 ^ (r & 7)) * 8;       // swizzled LDS col
                float4 g0 = *(const float4*)(nrow + 8 * c8);
                float4 g1 = *(const float4*)(nrow + 8 * c8 + 4);
                ushort4 k0, k1;
                k0.x = f2bf(__expf(g0.x - mr) * li); k0.y = f2bf(__expf(g0.y - mr) * li);
                k0.z = f2bf(__expf(g0.z - mr) * li); k0.w = f2bf(__expf(g0.w - mr) * li);
                k1.x = f2bf(__expf(g1.x - mr) * li); k1.y = f2bf(__expf(g1.y - mr) * li);
                k1.z = f2bf(__expf(g1.z - mr) * li); k1.w = f2bf(__expf(g1.w - mr) * li);
                *(ushort4*)&nks[r][sc]     = k0;
                *(ushort4*)&nks[r][sc + 4] = k1;
                ushort4 h0 = *(const ushort4*)(vrow + 8 * c8);
                ushort4 h1 = *(const ushort4*)(vrow + 8 * c8 + 4);
                *(ushort4*)&vls[r][sc]     = h0;
                *(ushort4*)&vls[r][sc + 4] = h1;
            }
        }
        __syncthreads();
        #pragma unroll
        for (int ks = 0; ks < 2; ks++) {
            const int kc = ((ks * 4 + quad) ^ (col & 7)) * 8;
            bf16x8 af = *(bf16x8*)&nks[w * 16 + col][kc];
            #pragma unroll
            for (int vt = 0; vt < 4; vt++) {
                bf16x8 bfr = *(bf16x8*)&vls[vt * 16 + col][kc];
                acc[vt] = __builtin_amdgcn_mfma_f32_16x16x32_bf16(af, bfr, acc[vt], 0, 0, 0);
            }
        }
    }
    // write: k = w*16 + quad*4 + rr (A-rows), v = vt*16 + col (B-rows)
    float* dst = clp + (((size_t)b * NTC_ + tc) * K_ + (w * 16 + quad * 4)) * V_ + v0;
    #pragma unroll
    for (int vt = 0; vt < 4; vt++)
        #pragma unroll
        for (int rr = 0; rr < 4; rr++)
            dst[(size_t)rr * V_ + vt * 16 + col] = acc[vt][rr];
}

// ---------------------------------------------------------------------------
// prep_cl3: sum clp partials; 4-way k-split over blockIdx.z;
// hterm accumulated via atomicAdd (zeroed in prep).
// ---------------------------------------------------------------------------
__global__ __launch_bounds__(256) void prep_cl_kernel3(
    const float* __restrict__ clp, const float* __restrict__ stat,
    const float* __restrict__ gq, const float* __restrict__ betaq,
    const float* __restrict__ gv, const float* __restrict__ betav,
    unsigned short* __restrict__ clb2, float* __restrict__ hterm)
{
    __shared__ float qsc[64], qsh[64], red[4][64];
    const int tid = threadIdx.x;
    const int b = blockIdx.y, v0 = blockIdx.x * 64, kz = blockIdx.z;
    const float inv_n = 1.f / (B_ * T_);
    if (tid < 64) {
        float mean = stat[tid] * inv_n;
        float var  = stat[64 + tid] * inv_n - mean * mean;
        float sc = gq[tid] * rsqrtf(var + EPS_);
        qsc[tid] = sc; qsh[tid] = betaq[tid] - mean * sc;
    }
    const int vl = tid & 63, kq = tid >> 6;
    const int c = v0 + vl;
    float vmean = stat[128 + c] * inv_n;
    float vvar  = stat[384 + c] * inv_n - vmean * vmean;
    float vsv = gv[c] * rsqrtf(vvar + EPS_);
    float vhv = betav[c] - vmean * vsv;
    __syncthreads();
    float h = 0.f;
    #pragma unroll
    for (int kk = 0; kk < 4; kk++) {
        int k = kz * 16 + kq * 4 + kk;
        float a = 0.f;
        #pragma unroll
        for (int tc = 0; tc < NTC_; tc++)
            a += clp[(((size_t)b * NTC_ + tc) * K_ + k) * V_ + c];
        float clbv = a * vsv + vhv;
        h += qsh[k] * clbv;
        clb2[((size_t)b * V_ + c) * K_ + k] = f2bf(clbv * qsc[k]);
    }
    red[kq][vl] = h;
    __syncthreads();
    if (tid < 64)
        atomicAdd(&hterm[(size_t)b * V_ + v0 + tid],
                  red[0][tid] + red[1][tid] + red[2][tid] + red[3][tid]);
}

// ---------------------------------------------------------------------------
// out_kernel9: R6/R7's PROVEN out_kernel7 (MFMA qpt, original conv loop);
// only change: vs2T fills from bf16 v_raw.
// ---------------------------------------------------------------------------
__global__ __launch_bounds__(256) void out_kernel9(
    const unsigned short* __restrict__ qT, const unsigned short* __restrict__ clb2,
    const float* __restrict__ hterm, const unsigned short* __restrict__ v_raw,
    const float* __restrict__ stat,
    const float* __restrict__ gq, const float* __restrict__ betaq,
    const float* __restrict__ gv, const float* __restrict__ betav,
    const float* __restrict__ pos_w, const float* __restrict__ pos_b,
    float* __restrict__ out)
{
    __shared__ unsigned short qTt[64][72];
    __shared__ unsigned short clv[64][72];
    __shared__ float vs2T[88][68];
    __shared__ float qpt[64][28];
    __shared__ unsigned short pwsT[32][72];
    __shared__ float qsc[64], qsh[64];
    __shared__ float consts[24];
    __shared__ float hvs[64];
    const int tid = threadIdx.x;
    const int b = blockIdx.z, v0 = blockIdx.y * 64, t0 = blockIdx.x * 64;
    const float inv_n = 1.f / (B_ * T_);

    if (tid < 64) {
        float mean = stat[tid] * inv_n;
        float var  = stat[64 + tid] * inv_n - mean * mean;
        float sc = gq[tid] * rsqrtf(var + EPS_);
        qsc[tid] = sc; qsh[tid] = betaq[tid] - mean * sc;
        hvs[tid] = hterm[(size_t)b * V_ + v0 + tid];
    }
    {
        const int rl = tid >> 2, part = tid & 3;
        const unsigned short* qs = qT + ((size_t)b * T_ + t0 + rl) * K_ + part * 16;
        *(bf16x8*)&qTt[rl][part * 16]     = *(const bf16x8*)(qs);
        *(bf16x8*)&qTt[rl][part * 16 + 8] = *(const bf16x8*)(qs + 8);
        const unsigned short* cs = clb2 + ((size_t)b * V_ + v0 + rl) * K_ + part * 16;
        *(bf16x8*)&clv[rl][part * 16]     = *(const bf16x8*)(cs);
        *(bf16x8*)&clv[rl][part * 16 + 8] = *(const bf16x8*)(cs + 8);
    }
    {
        const int vl = tid >> 2, qq = tid & 3;
        const int c = v0 + vl;
        float vmean = stat[128 + c] * inv_n;
        float vvar  = stat[384 + c] * inv_n - vmean * vmean;
        float vsv = gv[c] * rsqrtf(vvar + EPS_);
        float vhv = betav[c] - vmean * vsv;
        const unsigned short* vrow = v_raw + ((size_t)b * V_ + c) * T_;
        #pragma unroll
        for (int i = 0; i < 22; i++) {
            int cc = qq + 4 * i;
            if (cc < 86) {
                int t = t0 + cc - 11;
                vs2T[cc][vl] = (t >= 0 && t < T_) ? bf2f(vrow[t]) * vsv + vhv : 0.f;
            }
        }
    }
    __syncthreads();

    // pwsT fill: pwsT[s][k] = bf16(qsc[k] * posw(k,s)); rows 24..31 zero
    for (int idx = tid; idx < 32 * 64; idx += 256) {
        int s = idx >> 6, k = idx & 63;
        float v = (s < KS_) ? pos_w[k * KS_ + s] : (s == KS_ ? pos_b[k] : 0.f);
        pwsT[s][k] = f2bf(qsc[k] * v);
    }
    if (tid < 24) {
        float cs = 0.f;
        for (int k = 0; k < K_; k++)
            cs += qsh[k] * (tid < KS_ ? pos_w[k * KS_ + tid] : pos_b[k]);
        consts[tid] = cs;
    }
    __syncthreads();

    const int lane = tid & 63, w = tid >> 6;
    const int col = lane & 15, quad = lane >> 4;

    // stage C: qpt via MFMA (wave w owns t-tile w*16..w*16+16)
    {
        f32x4 aq[2];
        #pragma unroll
        for (int st = 0; st < 2; st++) {
            int s = st * 16 + col;
            float cv = (s < 24) ? consts[s] : 0.f;
            aq[st] = (f32x4){cv, cv, cv, cv};
        }
        #pragma unroll
        for (int ks = 0; ks < 2; ks++) {
            bf16x8 af = *(bf16x8*)&qTt[w * 16 + col][ks * 32 + quad * 8];
            #pragma unroll
            for (int st = 0; st < 2; st++) {
                bf16x8 bfr = *(bf16x8*)&pwsT[st * 16 + col][ks * 32 + quad * 8];
                aq[st] = __builtin_amdgcn_mfma_f32_16x16x32_bf16(af, bfr, aq[st], 0, 0, 0);
            }
        }
        #pragma unroll
        for (int st = 0; st < 2; st++) {
            int s = st * 16 + col;
            if (s < 24) {
                #pragma unroll
                for (int r = 0; r < 4; r++)
                    qpt[w * 16 + quad * 4 + r][s] = aq[st][r];
            }
        }
    }
    __syncthreads();

    // stage D: content MFMA + conv epilogue
    f32x4 acc[4];
    #pragma unroll
    for (int tf = 0; tf < 4; tf++) acc[tf] = (f32x4){0.f, 0.f, 0.f, 0.f};

    #pragma unroll
    for (int ks = 0; ks < 2; ks++) {
        const int kc = ks * 32 + quad * 8;
        bf16x8 af = *(bf16x8*)&clv[w * 16 + col][kc];
        #pragma unroll
        for (int tf = 0; tf < 4; tf++) {
            bf16x8 bq = *(bf16x8*)&qTt[tf * 16 + col][kc];
            acc[tf] = __builtin_amdgcn_mfma_f32_16x16x32_bf16(af, bq, acc[tf], 0, 0, 0);
        }
    }

    const int vb = w * 16 + quad * 4;
    float4 hv4 = *(float4*)&hvs[vb];
    #pragma unroll
    for (int tf = 0; tf < 4; tf++) {
        const int lt = tf * 16 + col;
        float qv[24];
        #pragma unroll
        for (int u = 0; u < 6; u++)
            *(float4*)&qv[4 * u] = *(float4*)&qpt[lt][4 * u];
        float4 a; a.x = acc[tf][0]; a.y = acc[tf][1]; a.z = acc[tf][2]; a.w = acc[tf][3];
        #pragma unroll
        for (int s = 0; s < KS_; s++) {
            float4 wv = *(float4*)&vs2T[lt + s][vb];
            a.x += qv[s] * wv.x; a.y += qv[s] * wv.y;
            a.z += qv[s] * wv.z; a.w += qv[s] * wv.w;
        }
        float base = qv[23];
        a.x += base + hv4.x; a.y += base + hv4.y;
        a.z += base + hv4.z; a.w += base + hv4.w;
        float* ap = (float*)&a;
        #pragma unroll
        for (int r = 0; r < 4; r++)
            out[((size_t)b * V_ + v0 + vb + r) * T_ + t0 + lt] = ap[r];
    }
}

extern "C" void kernel_launch(void* const* d_in, const int* in_sizes, int n_in,
                              void* d_out, int out_size, void* d_ws, size_t ws_size,
                              hipStream_t stream)
{
    const float* x     = (const float*)d_in[0];
    const float* ctx   = (const float*)d_in[1];
    const float* Wq    = (const float*)d_in[2];
    const float* bq    = (const float*)d_in[3];
    const float* Wk    = (const float*)d_in[4];
    const float* bk    = (const float*)d_in[5];
    const float* Wv    = (const float*)d_in[6];
    const float* bv    = (const float*)d_in[7];
    const float* gq    = (const float*)d_in[8];
    const float* betaq = (const float*)d_in[9];
    const float* gv    = (const float*)d_in[10];
    const float* betav = (const float*)d_in[11];
    const float* pos_w = (const float*)d_in[12];
    const float* pos_b = (const float*)d_in[13];
    float* out = (float*)d_out;

    float* ws    = (float*)d_ws;
    float* k_buf = ws;                                             // B*K*T f32
    unsigned short* v_raw = (unsigned short*)(k_buf + (size_t)B_ * K_ * T_);  // B*V*T bf16
    float* clp   = (float*)(v_raw + (size_t)B_ * V_ * T_);         // B*NTC*K*V f32
    float* stat  = clp + (size_t)B_ * NTC_ * K_ * V_;              // 640
    float* hterm = stat + 640;                                     // B*V = 2048
    float* kml   = hterm + (size_t)B_ * V_;                        // B*K*8*2
    unsigned short* xT   = (unsigned short*)(kml + (size_t)B_ * K_ * 16);
    unsigned short* cT   = xT + (size_t)B_ * T_ * CIN_;
    unsigned short* Wb   = cT + (size_t)B_ * T_ * CIN_;
    unsigned short* qT   = Wb + (size_t)(2 * K_ + V_) * CIN_;
    unsigned short* clb2 = qT + (size_t)B_ * T_ * K_;

    prep_kernel<<<dim3(2048 + 192), 256, 0, stream>>>(
        x, ctx, Wq, Wk, Wv, xT, cT, Wb, stat);
    proj_mfma8<<<dim3(T_ / 128, 6, B_), 256, 0, stream>>>(
        xT, cT, Wb, bq, bk, bv, k_buf, v_raw, qT, stat, kml);
    lambda_kernel10<<<dim3(NTC_, V_ / 64, B_), 256, 0, stream>>>(k_buf, v_raw, kml, clp);
    prep_cl_kernel3<<<dim3(V_ / 64, B_, 4), 256, 0, stream>>>(
        clp, stat, gq, betaq, gv, betav, clb2, hterm);
    out_kernel9<<<dim3(T_ / 64, V_ / 64, B_), 256, 0, stream>>>(
        qT, clb2, hterm, v_raw, stat, gq, betaq, gv, betav, pos_w, pos_b, out);
}